// Round 2
// baseline (913.383 us; speedup 1.0000x reference)
//
#include <hip/hip_runtime.h>
#include <math.h>

// Problem constants
#define NN    100000
#define EPOS  250000
#define ENEG  250000
#define ENON  500000
#define E3   1000000
#define NLSE  4096

// Workspace layout (bytes, 16B-aligned)
#define ACC_OFF 0
#define LSE_OFF 64
#define X0_OFF  (LSE_OFF + NLSE * 16)        // 65600
#define Y_OFF   (X0_OFF + NN * 4)            // 465600
#define ZA_OFF  (Y_OFF + NN * 64 * 4)        // 26065600
#define ZB_OFF  (ZA_OFF + NN * 16)           // 27665600
#define PQ_OFF  (ZB_OFF + NN * 16)           // 29265600
#define WS_NEED ((size_t)PQ_OFF + (size_t)NN * 264 * 4)  // ~134.9 MB

// acc slots: 0=nll, 1=l1_sum, 2=l2_sum, 3=s1(pred sum), 4-7 spare

__device__ __forceinline__ float wredf(float v) {
#pragma unroll
  for (int m = 32; m; m >>= 1) v += __shfl_xor(v, m, 64);
  return v;
}

__device__ __forceinline__ void breduce2(double v0, double v1, double* g0, double* g1,
                                         double* rbuf) {
#pragma unroll
  for (int m = 32; m; m >>= 1) {
    v0 += __shfl_xor(v0, m, 64);
    v1 += __shfl_xor(v1, m, 64);
  }
  int l = threadIdx.x & 63, w = threadIdx.x >> 6;
  if (l == 0) { rbuf[2 * w] = v0; rbuf[2 * w + 1] = v1; }
  __syncthreads();
  if (threadIdx.x == 0) {
    int nw = blockDim.x >> 6;
    double s0 = 0.0, s1 = 0.0;
    for (int i = 0; i < nw; ++i) { s0 += rbuf[2 * i]; s1 += rbuf[2 * i + 1]; }
    atomicAdd(g0, s0);
    atomicAdd(g1, s1);
  }
}

// Online log-sum-exp pair combine: (m,s) <- combine((m,s),(om,os)); guarded for -inf.
__device__ __forceinline__ void lse_combine(double& m, double& s, double om, double os) {
  double M = fmax(m, om);
  double sn = 0.0;
  if (m > -INFINITY) sn += s * exp(m - M);
  if (om > -INFINITY) sn += os * exp(om - M);
  m = M;
  s = sn;
}

// Reduce (lm,ls) across the block, write this block's pair to out_pair[0..1].
__device__ __forceinline__ void lse_block_reduce(double lm, double ls, double* out_pair,
                                                 double* rbuf) {
#pragma unroll
  for (int d = 32; d; d >>= 1) {
    double om = __shfl_xor(lm, d, 64);
    double os = __shfl_xor(ls, d, 64);
    lse_combine(lm, ls, om, os);
  }
  __syncthreads();  // rbuf may be in use by a previous reduction
  int l = threadIdx.x & 63, w = threadIdx.x >> 6;
  if (l == 0) { rbuf[2 * w] = lm; rbuf[2 * w + 1] = ls; }
  __syncthreads();
  if (threadIdx.x == 0) {
    int nw = blockDim.x >> 6;
    double M = rbuf[0], S = rbuf[1];
    for (int i = 1; i < nw; ++i) lse_combine(M, S, rbuf[2 * i], rbuf[2 * i + 1]);
    out_pair[0] = M;
    out_pair[1] = S;
  }
}

// Stage w1 (130x131) into LDS as two 130x68 matrices:
// WA[k][d] = w1[k][1+d] (d<64), WA[k][64] = w1[k][0]  (x0 coefficient), pads 65..67 = 0
// WB[k][d] = w1[k][66+d] (d<64), WB[k][64] = w1[k][65]
__device__ __forceinline__ void stage_w1(const float* __restrict__ w1, float* WS) {
  for (int idx = threadIdx.x; idx < 2 * 130 * 68; idx += blockDim.x) {
    int half = idx >= 130 * 68;
    int rem = idx - half * (130 * 68);
    int k = rem / 68, d = rem - k * 68;
    const float* row = w1 + k * 131 + (half ? 65 : 0);
    float v = 0.f;
    if (d < 64) v = row[1 + d];
    else if (d == 64) v = row[0];
    WS[idx] = v;
  }
}

__global__ void k_zero(double* acc, double* lse) {
  int idx = blockIdx.x * blockDim.x + threadIdx.x;
  if (idx < 8) acc[idx] = 0.0;
  if (idx < NLSE) {
    lse[2 * idx] = -INFINITY;
    lse[2 * idx + 1] = 0.0;
  }
}

// Per-node precompute: y/x0, za/zb (discriminator folds), P/Q (info_net layer-1 folds).
// Block = 256 (4 waves); each wave handles 4 nodes; grid = NN/16 = 6250 exact.
__global__ __launch_bounds__(256, 2) void k_precompute(
    const float* __restrict__ z, const float* __restrict__ lin_w,
    const float* __restrict__ w1,
    float* __restrict__ Y, float* __restrict__ X0,
    float4* __restrict__ ZA4, float4* __restrict__ ZB4,
    float* __restrict__ PQ, int do_pq) {
  __shared__ float WS[2 * 130 * 68];  // 70,720 B
  if (do_pq) stage_w1(w1, WS);
  __syncthreads();
  const int l = threadIdx.x & 63;
  const int w = threadIdx.x >> 6;
  const int nbase = blockIdx.x * 16 + w * 4;

  float ym[4], x0v[4];
#pragma unroll
  for (int m = 0; m < 4; ++m) {
    const int n = nbase + m;
    float zv = z[(size_t)n * 64 + l];
    float zn2 = wredf(zv * zv);
    float xn = fmaxf(sqrtf(zn2), 1e-15f);
    float th = xn * 1.7320508075688772f;          // theta = xn / sqrt(K)
    float fac = 0.5773502691896258f * sinhf(th) / xn;
    float y = fac * zv;
    float yn2 = wredf(y * y);
    float x0 = sqrtf(0.33333333333333333f + yn2); // hyp_proj
    Y[(size_t)n * 64 + l] = y;
    ym[m] = y;
    x0v[m] = x0;
    float za0 = wredf(zv * lin_w[l]);
    float za1 = wredf(zv * lin_w[128 + l]);
    float za2 = wredf(zv * lin_w[256 + l]);
    float zb0 = wredf(zv * lin_w[64 + l]);
    float zb1 = wredf(zv * lin_w[192 + l]);
    float zb2 = wredf(zv * lin_w[320 + l]);
    if (l == 0) {
      X0[n] = x0;
      ZA4[n] = make_float4(za0, za1, za2, 0.f);
      ZB4[n] = make_float4(zb0, zb1, zb2, 0.f);
    }
  }
  if (!do_pq) return;

  // PQ phase: flat output id o in [0,260): o<130 -> P[k=o], else Q[k=o-130].
  // Lane l owns o = l+64r (r=0..3) plus lanes 0..3 own o=256+l.
  const float* rowp[4];
#pragma unroll
  for (int r = 0; r < 4; ++r) {
    int o = l + 64 * r;
    rowp[r] = (o < 130) ? (WS + o * 68) : (WS + 130 * 68 + (o - 130) * 68);
  }
  const bool act4 = (l < 4);
  const float* rowp4 = act4 ? (WS + 130 * 68 + (126 + l) * 68) : WS;

  float acc[4][4] = {{0.f}};
  float acc4[4] = {0.f, 0.f, 0.f, 0.f};
  for (int c = 0; c < 16; ++c) {
    float ybc[4][4];
#pragma unroll
    for (int m = 0; m < 4; ++m) {
#pragma unroll
      for (int i = 0; i < 4; ++i) ybc[m][i] = __shfl(ym[m], 4 * c + i, 64);
    }
#pragma unroll
    for (int r = 0; r < 4; ++r) {
      float4 w4 = *(const float4*)(rowp[r] + 4 * c);
#pragma unroll
      for (int m = 0; m < 4; ++m)
        acc[r][m] += w4.x * ybc[m][0] + w4.y * ybc[m][1] + w4.z * ybc[m][2] + w4.w * ybc[m][3];
    }
    if (act4) {
      float4 w4 = *(const float4*)(rowp4 + 4 * c);
#pragma unroll
      for (int m = 0; m < 4; ++m)
        acc4[m] += w4.x * ybc[m][0] + w4.y * ybc[m][1] + w4.z * ybc[m][2] + w4.w * ybc[m][3];
    }
  }
  // x0 tail + writes. PQ node layout: P at [0..131] (130,131 pad), Q at [132..263].
#pragma unroll
  for (int r = 0; r < 4; ++r) {
    float wx = rowp[r][64];
    int o = l + 64 * r;
    int off = (o < 130) ? o : (o + 2);
#pragma unroll
    for (int m = 0; m < 4; ++m)
      PQ[(size_t)(nbase + m) * 264 + off] = acc[r][m] + x0v[m] * wx;
  }
  if (act4) {
    float wx = rowp4[64];
    int off = 258 + l;  // o=256+l -> Q k=126+l
#pragma unroll
    for (int m = 0; m < 4; ++m)
      PQ[(size_t)(nbase + m) * 264 + off] = acc4[m] + x0v[m] * wx;
  }
  if (l >= 4 && l < 8) {
    int pid = l - 4;
    int poff = (pid < 2) ? (130 + pid) : (260 + pid);  // pads 130,131,262,263
#pragma unroll
    for (int m = 0; m < 4; ++m)
      PQ[(size_t)(nbase + m) * 264 + poff] = 0.f;
  }
}

// nll over 1M edges (pos target0, neg target1, none target2), thread-per-edge.
__global__ __launch_bounds__(256) void k_nll(
    const int* __restrict__ p0, const int* __restrict__ p1,
    const int* __restrict__ n0, const int* __restrict__ n1,
    const int* __restrict__ o0, const int* __restrict__ o1,
    const float4* __restrict__ ZA4, const float4* __restrict__ ZB4,
    const float* __restrict__ lin_b, double* __restrict__ acc) {
  __shared__ double rbuf[8];
  const float c0 = lin_b[0], c1 = lin_b[1], c2 = lin_b[2];
  const float wp = 1.f / (3.f * EPOS), wn = 1.f / (3.f * ENEG), wo = 1.f / (3.f * ENON);
  double s = 0.0;
  for (int e = blockIdx.x * blockDim.x + threadIdx.x; e < E3; e += gridDim.x * blockDim.x) {
    int i, j, tgt;
    float wgt;
    if (e < EPOS) { i = p0[e]; j = p1[e]; tgt = 0; wgt = wp; }
    else if (e < EPOS + ENEG) { int t = e - EPOS; i = n0[t]; j = n1[t]; tgt = 1; wgt = wn; }
    else { int t = e - EPOS - ENEG; i = o0[t]; j = o1[t]; tgt = 2; wgt = wo; }
    float4 a = ZA4[i], b = ZB4[j];
    float l0 = a.x + b.x + c0, l1 = a.y + b.y + c1, l2 = a.z + b.z + c2;
    float mx = fmaxf(l0, fmaxf(l1, l2));
    float lse = mx + logf(expf(l0 - mx) + expf(l1 - mx) + expf(l2 - mx));
    float lt = (tgt == 0) ? l0 : ((tgt == 1) ? l1 : l2);
    s += (double)((lse - lt) * wgt);
  }
  breduce2(s, 0.0, acc + 0, acc + 5, rbuf);
}

__device__ __forceinline__ float hsq(float mdot) {
  float th = fmaxf(-3.f * mdot, 1.f + 1e-7f);
  float ach = logf(th + sqrtf(th * th - 1.f));
  return fminf(ach * ach * (1.f / 3.f), 50.f);
}

// l1/l2 hinge terms: 16 lanes per edge, dot over 64 dims via float4.
__global__ __launch_bounds__(256) void k_struct(
    const int* __restrict__ p0, const int* __restrict__ p1, const int* __restrict__ pk,
    const int* __restrict__ n0, const int* __restrict__ n1, const int* __restrict__ nk,
    const float4* __restrict__ Y4, const float* __restrict__ X0, double* __restrict__ acc) {
  __shared__ double rbuf[8];
  const int st = threadIdx.x & 15;
  int g = (blockIdx.x * blockDim.x + threadIdx.x) >> 4;
  const int gs = (gridDim.x * blockDim.x) >> 4;
  double s1 = 0.0, s2 = 0.0;
  for (int e = g; e < EPOS + ENEG; e += gs) {
    bool pos = e < EPOS;
    int i, j, kk;
    if (pos) { i = p0[e]; j = p1[e]; kk = pk[e]; }
    else { int t = e - EPOS; i = n0[t]; j = n1[t]; kk = nk[t]; }
    float4 yi = Y4[(size_t)i * 16 + st];
    float4 yj = Y4[(size_t)j * 16 + st];
    float4 yk = Y4[(size_t)kk * 16 + st];
    float dij = yi.x * yj.x + yi.y * yj.y + yi.z * yj.z + yi.w * yj.w;
    float dik = yi.x * yk.x + yi.y * yk.y + yi.z * yk.z + yi.w * yk.w;
#pragma unroll
    for (int m = 8; m; m >>= 1) {
      dij += __shfl_xor(dij, m, 64);
      dik += __shfl_xor(dik, m, 64);
    }
    if (st == 0) {
      float x0i = X0[i], x0j = X0[j], x0k = X0[kk];
      float sij = hsq(dij - x0i * x0j);
      float sik = hsq(dik - x0i * x0k);
      if (pos) s1 += (double)fmaxf(sij - sik, 0.f);
      else s2 += (double)fmaxf(sik - sij, 0.f);
    }
  }
  breduce2(s1, s2, acc + 1, acc + 2, rbuf);
}

// l3 via PQ gathers: 32 lanes per edge; A = P[i] + Q[j]; two relu-dot passes share A.
// Shuffle-branch exp sum kept as a stable streaming LSE (reference overflows to inf;
// we produce the mathematically-exact finite value).
__global__ __launch_bounds__(256) void k_info(
    const int* __restrict__ p0, const int* __restrict__ p1,
    const int* __restrict__ n0, const int* __restrict__ n1,
    const int* __restrict__ q0, const int* __restrict__ q1,
    const int* __restrict__ perm,
    const float4* __restrict__ PQ4,
    const float* __restrict__ w1, const float* __restrict__ b1v,
    const float* __restrict__ w2v, const float* __restrict__ b2v,
    double* __restrict__ acc, double* __restrict__ lse) {
  __shared__ __align__(16) float BY[3][132];
  __shared__ __align__(16) float W2S[132];
  __shared__ float b2sh;
  __shared__ double rbuf[8];
  __shared__ double rbuf2[8];
  for (int k = threadIdx.x; k < 132; k += blockDim.x) {
    float bb = (k < 130) ? b1v[k] : 0.f;
    float wy = (k < 130) ? w1[k * 131 + 130] : 0.f;
    float w2k = (k < 130) ? w2v[k] : 0.f;
    BY[0][k] = bb;
    BY[1][k] = bb + wy;
    BY[2][k] = bb + 2.f * wy;
    W2S[k] = w2k;
  }
  if (threadIdx.x == 0) b2sh = b2v[0];
  __syncthreads();
  const double b2 = (double)b2sh;
  const float b2f = b2sh;
  const int st = threadIdx.x & 31;
  int g = (blockIdx.x * blockDim.x + threadIdx.x) >> 5;
  const int gs = (gridDim.x * blockDim.x) >> 5;
  double s1 = 0.0;
  double lm = -INFINITY, ls = 0.0;
  for (int e = g; e < E3; e += gs) {
    int i, j, ypi;
    if (e < EPOS) { i = p0[e]; j = p1[e]; ypi = 0; }
    else if (e < EPOS + ENEG) { int t = e - EPOS; i = n0[t]; j = n1[t]; ypi = 1; }
    else { int t = e - EPOS - ENEG; i = q0[t]; j = q1[t]; ypi = 2; }
    int p = perm[e];
    int ysi = (p < EPOS) ? 0 : ((p < EPOS + ENEG) ? 1 : 2);
    size_t bi = (size_t)i * 66, bj = (size_t)j * 66 + 33;
    float4 pa = PQ4[bi + st], qa = PQ4[bj + st];
    float4 A;
    A.x = pa.x + qa.x; A.y = pa.y + qa.y; A.z = pa.z + qa.z; A.w = pa.w + qa.w;
    float4 byP = ((const float4*)BY[ypi])[st];
    float4 byS = ((const float4*)BY[ysi])[st];
    float4 w24 = ((const float4*)W2S)[st];
    float sp = fmaxf(A.x + byP.x, 0.f) * w24.x + fmaxf(A.y + byP.y, 0.f) * w24.y +
               fmaxf(A.z + byP.z, 0.f) * w24.z + fmaxf(A.w + byP.w, 0.f) * w24.w;
    float ss = fmaxf(A.x + byS.x, 0.f) * w24.x + fmaxf(A.y + byS.y, 0.f) * w24.y +
               fmaxf(A.z + byS.z, 0.f) * w24.z + fmaxf(A.w + byS.w, 0.f) * w24.w;
    if (st == 0) {  // chunk 32 (k=128..131; 130,131 are zero pads)
      float4 pa2 = PQ4[bi + 32], qa2 = PQ4[bj + 32];
      float4 A2;
      A2.x = pa2.x + qa2.x; A2.y = pa2.y + qa2.y; A2.z = pa2.z + qa2.z; A2.w = pa2.w + qa2.w;
      float4 bp2 = ((const float4*)BY[ypi])[32];
      float4 bs2 = ((const float4*)BY[ysi])[32];
      float4 w22 = ((const float4*)W2S)[32];
      sp += fmaxf(A2.x + bp2.x, 0.f) * w22.x + fmaxf(A2.y + bp2.y, 0.f) * w22.y +
            fmaxf(A2.z + bp2.z, 0.f) * w22.z + fmaxf(A2.w + bp2.w, 0.f) * w22.w;
      ss += fmaxf(A2.x + bs2.x, 0.f) * w22.x + fmaxf(A2.y + bs2.y, 0.f) * w22.y +
            fmaxf(A2.z + bs2.z, 0.f) * w22.z + fmaxf(A2.w + bs2.w, 0.f) * w22.w;
    }
#pragma unroll
    for (int m = 16; m; m >>= 1) {
      sp += __shfl_xor(sp, m, 64);
      ss += __shfl_xor(ss, m, 64);
    }
    if (st == 0) {
      s1 += (double)(sp + b2f);
      double v = (double)ss + b2;
      if (v > lm) { ls = ls * exp(lm - v) + 1.0; lm = v; }
      else ls += exp(v - lm);
    }
  }
  breduce2(s1, 0.0, acc + 3, acc + 6, rbuf);
  lse_block_reduce(lm, ls, lse + 2 * blockIdx.x, rbuf2);
}

// Fallback l3 (if workspace too small for PQ): per-edge matvec against LDS-staged w1.
__global__ __launch_bounds__(256, 2) void k_info_direct(
    const int* __restrict__ p0, const int* __restrict__ p1,
    const int* __restrict__ n0, const int* __restrict__ n1,
    const int* __restrict__ q0, const int* __restrict__ q1,
    const int* __restrict__ perm,
    const float4* __restrict__ Y4, const float* __restrict__ X0,
    const float* __restrict__ w1, const float* __restrict__ b1v,
    const float* __restrict__ w2v, const float* __restrict__ b2v,
    double* __restrict__ acc, double* __restrict__ lse) {
  __shared__ float WS[2 * 130 * 68];
  __shared__ float BY[3][132];
  __shared__ float W2S[132];
  __shared__ float b2sh;
  __shared__ double rbuf[8];
  __shared__ double rbuf2[8];
  stage_w1(w1, WS);
  for (int k = threadIdx.x; k < 132; k += blockDim.x) {
    float bb = (k < 130) ? b1v[k] : 0.f;
    float wy = (k < 130) ? w1[k * 131 + 130] : 0.f;
    float w2k = (k < 130) ? w2v[k] : 0.f;
    BY[0][k] = bb;
    BY[1][k] = bb + wy;
    BY[2][k] = bb + 2.f * wy;
    W2S[k] = w2k;
  }
  if (threadIdx.x == 0) b2sh = b2v[0];
  __syncthreads();
  const double b2 = (double)b2sh;
  const float b2f = b2sh;
  const int st = threadIdx.x & 31;
  int g = (blockIdx.x * blockDim.x + threadIdx.x) >> 5;
  const int gs = (gridDim.x * blockDim.x) >> 5;
  double s1 = 0.0;
  double lm = -INFINITY, ls = 0.0;
  for (int e = g; e < E3; e += gs) {
    int i, j, ypi;
    if (e < EPOS) { i = p0[e]; j = p1[e]; ypi = 0; }
    else if (e < EPOS + ENEG) { int t = e - EPOS; i = n0[t]; j = n1[t]; ypi = 1; }
    else { int t = e - EPOS - ENEG; i = q0[t]; j = q1[t]; ypi = 2; }
    int p = perm[e];
    int ysi = (p < EPOS) ? 0 : ((p < EPOS + ENEG) ? 1 : 2);
    float x0i = X0[i], x0j = X0[j];
    float a[4] = {0.f, 0.f, 0.f, 0.f};
    float a128 = 0.f, a129 = 0.f;
    for (int c = 0; c < 16; ++c) {
      float4 yi4 = Y4[(size_t)i * 16 + c];
      float4 yj4 = Y4[(size_t)j * 16 + c];
#pragma unroll
      for (int q = 0; q < 4; ++q) {
        int k = st + 32 * q;  // lane-consecutive k avoids LDS bank conflicts
        float4 wa = *(const float4*)(WS + k * 68 + 4 * c);
        float4 wb = *(const float4*)(WS + 130 * 68 + k * 68 + 4 * c);
        a[q] += wa.x * yi4.x + wa.y * yi4.y + wa.z * yi4.z + wa.w * yi4.w +
                wb.x * yj4.x + wb.y * yj4.y + wb.z * yj4.z + wb.w * yj4.w;
      }
      if (st == 0) {
        float4 wa = *(const float4*)(WS + 128 * 68 + 4 * c);
        float4 wb = *(const float4*)(WS + 130 * 68 + 128 * 68 + 4 * c);
        a128 += wa.x * yi4.x + wa.y * yi4.y + wa.z * yi4.z + wa.w * yi4.w +
                wb.x * yj4.x + wb.y * yj4.y + wb.z * yj4.z + wb.w * yj4.w;
        float4 wc = *(const float4*)(WS + 129 * 68 + 4 * c);
        float4 wd = *(const float4*)(WS + 130 * 68 + 129 * 68 + 4 * c);
        a129 += wc.x * yi4.x + wc.y * yi4.y + wc.z * yi4.z + wc.w * yi4.w +
                wd.x * yj4.x + wd.y * yj4.y + wd.z * yj4.z + wd.w * yj4.w;
      }
    }
#pragma unroll
    for (int q = 0; q < 4; ++q) {
      int k = st + 32 * q;
      a[q] += x0i * WS[k * 68 + 64] + x0j * WS[130 * 68 + k * 68 + 64];
    }
    if (st == 0) {
      a128 += x0i * WS[128 * 68 + 64] + x0j * WS[130 * 68 + 128 * 68 + 64];
      a129 += x0i * WS[129 * 68 + 64] + x0j * WS[130 * 68 + 129 * 68 + 64];
    }
    float sp = 0.f, ss = 0.f;
#pragma unroll
    for (int q = 0; q < 4; ++q) {
      int k = st + 32 * q;
      float byp = BY[ypi][k], bys = BY[ysi][k], w2k = W2S[k];
      sp += fmaxf(a[q] + byp, 0.f) * w2k;
      ss += fmaxf(a[q] + bys, 0.f) * w2k;
    }
    if (st == 0) {
      sp += fmaxf(a128 + BY[ypi][128], 0.f) * W2S[128] + fmaxf(a129 + BY[ypi][129], 0.f) * W2S[129];
      ss += fmaxf(a128 + BY[ysi][128], 0.f) * W2S[128] + fmaxf(a129 + BY[ysi][129], 0.f) * W2S[129];
    }
#pragma unroll
    for (int m = 16; m; m >>= 1) {
      sp += __shfl_xor(sp, m, 64);
      ss += __shfl_xor(ss, m, 64);
    }
    if (st == 0) {
      s1 += (double)(sp + b2f);
      double v = (double)ss + b2;
      if (v > lm) { ls = ls * exp(lm - v) + 1.0; lm = v; }
      else ls += exp(v - lm);
    }
  }
  breduce2(s1, 0.0, acc + 3, acc + 6, rbuf);
  lse_block_reduce(lm, ls, lse + 2 * blockIdx.x, rbuf2);
}

__global__ void k_final(const double* __restrict__ acc, const double* __restrict__ lse,
                        float* __restrict__ out) {
  __shared__ double rb[8];
  double lm = -INFINITY, ls = 0.0;
  for (int i = threadIdx.x; i < NLSE; i += blockDim.x)
    lse_combine(lm, ls, lse[2 * i], lse[2 * i + 1]);
#pragma unroll
  for (int d = 32; d; d >>= 1) {
    double om = __shfl_xor(lm, d, 64);
    double os = __shfl_xor(ls, d, 64);
    lse_combine(lm, ls, om, os);
  }
  int l = threadIdx.x & 63, w = threadIdx.x >> 6;
  if (l == 0) { rb[2 * w] = lm; rb[2 * w + 1] = ls; }
  __syncthreads();
  if (threadIdx.x == 0) {
    double M = rb[0], S = rb[1];
    int nw = blockDim.x >> 6;
    for (int i = 1; i < nw; ++i) lse_combine(M, S, rb[2 * i], rb[2 * i + 1]);
    // log(mean(exp(shuffle))) computed stably (reference overflows to +inf here)
    double logmean = M + log(S) - log((double)E3);
    double nll = acc[0];
    double l1 = acc[1] / (double)EPOS;
    double l2 = acc[2] / (double)ENEG;
    double s1m = acc[3] / (double)E3;
    double l3 = -(s1m - logmean);
    out[0] = (float)(nll + 5.0 * (l1 + l2) + 0.1 * l3);
  }
}

extern "C" void kernel_launch(void* const* d_in, const int* in_sizes, int n_in,
                              void* d_out, int out_size, void* d_ws, size_t ws_size,
                              hipStream_t stream) {
  const float* z     = (const float*)d_in[0];
  const float* lin_w = (const float*)d_in[1];
  const float* lin_b = (const float*)d_in[2];
  const float* w1    = (const float*)d_in[3];
  const float* b1v   = (const float*)d_in[4];
  const float* w2v   = (const float*)d_in[5];
  const float* b2v   = (const float*)d_in[6];
  const int* pos  = (const int*)d_in[7];
  const int* neg  = (const int*)d_in[8];
  const int* non  = (const int*)d_in[9];
  const int* non2 = (const int*)d_in[10];
  const int* posk = (const int*)d_in[11];
  const int* negk = (const int*)d_in[12];
  const int* perm = (const int*)d_in[13];

  char* ws = (char*)d_ws;
  double* acc = (double*)(ws + ACC_OFF);
  double* lse = (double*)(ws + LSE_OFF);
  float* X0   = (float*)(ws + X0_OFF);
  float* Y    = (float*)(ws + Y_OFF);
  float4* ZA4 = (float4*)(ws + ZA_OFF);
  float4* ZB4 = (float4*)(ws + ZB_OFF);
  float* PQ   = (float*)(ws + PQ_OFF);
  const int do_pq = (ws_size >= WS_NEED) ? 1 : 0;

  hipLaunchKernelGGL(k_zero, dim3(16), dim3(256), 0, stream, acc, lse);
  hipLaunchKernelGGL(k_precompute, dim3(NN / 16), dim3(256), 0, stream,
                     z, lin_w, w1, Y, X0, ZA4, ZB4, PQ, do_pq);
  hipLaunchKernelGGL(k_nll, dim3(2048), dim3(256), 0, stream,
                     pos, pos + EPOS, neg, neg + ENEG, non, non + ENON, ZA4, ZB4, lin_b, acc);
  hipLaunchKernelGGL(k_struct, dim3(4096), dim3(256), 0, stream,
                     pos, pos + EPOS, posk, neg, neg + ENEG, negk,
                     (const float4*)Y, X0, acc);
  if (do_pq) {
    hipLaunchKernelGGL(k_info, dim3(4096), dim3(256), 0, stream,
                       pos, pos + EPOS, neg, neg + ENEG, non2, non2 + ENON, perm,
                       (const float4*)PQ, w1, b1v, w2v, b2v, acc, lse);
  } else {
    hipLaunchKernelGGL(k_info_direct, dim3(2048), dim3(256), 0, stream,
                       pos, pos + EPOS, neg, neg + ENEG, non2, non2 + ENON, perm,
                       (const float4*)Y, X0, w1, b1v, w2v, b2v, acc, lse);
  }
  hipLaunchKernelGGL(k_final, dim3(1), dim3(256), 0, stream, acc, lse, (float*)d_out);
}

// Round 3
// 455.405 us; speedup vs baseline: 2.0057x; 2.0057x over previous
//
#include <hip/hip_runtime.h>
#include <math.h>

// Problem constants
#define NN    100000
#define EPOS  250000
#define ENEG  250000
#define ENON  500000
#define E3   1000000
#define NLSE  4096

// Workspace layout (bytes, 256B-aligned sections)
#define ACC_OFF 0
#define LSE_OFF 256                    // 4096*16 = 65,536 -> ends 65,792
#define X0_OFF  66048                  // 400,000       -> ends 466,048
#define YBF_OFF 466176                 // 100k*96*2 = 19,200,000 -> ends 19,666,176
#define ZA_OFF  19666176               // 1,600,000 -> 21,266,176
#define ZB_OFF  21266176               // 1,600,000 -> 22,866,176
#define WT_OFF  22866176               // 57,344 (272x104 bf16 padded) -> 22,923,520
#define PQ_OFF  22923776               // 100k*272*2 = 54,400,000 -> ~77.3 MB total

typedef __attribute__((ext_vector_type(8))) short bh8;
typedef __attribute__((ext_vector_type(4))) float f32x4;

// acc slots: 0=nll, 1=l1_sum, 2=l2_sum, 3=s1(pred sum), 5/6 dummies

__device__ __forceinline__ unsigned short f2bf(float f) {
  unsigned u = __float_as_uint(f);
  unsigned r = (u + 0x7FFFu + ((u >> 16) & 1u)) >> 16;
  return (unsigned short)r;
}
__device__ __forceinline__ float b2f(unsigned short s) {
  return __uint_as_float(((unsigned)s) << 16);
}

__device__ __forceinline__ void breduce2(double v0, double v1, double* g0, double* g1,
                                         double* rbuf) {
#pragma unroll
  for (int m = 32; m; m >>= 1) {
    v0 += __shfl_xor(v0, m, 64);
    v1 += __shfl_xor(v1, m, 64);
  }
  int l = threadIdx.x & 63, w = threadIdx.x >> 6;
  if (l == 0) { rbuf[2 * w] = v0; rbuf[2 * w + 1] = v1; }
  __syncthreads();
  if (threadIdx.x == 0) {
    int nw = blockDim.x >> 6;
    double s0 = 0.0, s1 = 0.0;
    for (int i = 0; i < nw; ++i) { s0 += rbuf[2 * i]; s1 += rbuf[2 * i + 1]; }
    atomicAdd(g0, s0);
    atomicAdd(g1, s1);
  }
}

// Online log-sum-exp pair combine, guarded for -inf.
__device__ __forceinline__ void lse_combine(double& m, double& s, double om, double os) {
  double M = fmax(m, om);
  double sn = 0.0;
  if (m > -INFINITY) sn += s * exp(m - M);
  if (om > -INFINITY) sn += os * exp(om - M);
  m = M;
  s = sn;
}

__device__ __forceinline__ void lse_block_reduce(double lm, double ls, double* out_pair,
                                                 double* rbuf) {
#pragma unroll
  for (int d = 32; d; d >>= 1) {
    double om = __shfl_xor(lm, d, 64);
    double os = __shfl_xor(ls, d, 64);
    lse_combine(lm, ls, om, os);
  }
  __syncthreads();
  int l = threadIdx.x & 63, w = threadIdx.x >> 6;
  if (l == 0) { rbuf[2 * w] = lm; rbuf[2 * w + 1] = ls; }
  __syncthreads();
  if (threadIdx.x == 0) {
    int nw = blockDim.x >> 6;
    double M = rbuf[0], S = rbuf[1];
    for (int i = 1; i < nw; ++i) lse_combine(M, S, rbuf[2 * i], rbuf[2 * i + 1]);
    out_pair[0] = M;
    out_pair[1] = S;
  }
}

// k_init: zero acc + lse pairs; build Wt_g [272 cols][104 k] bf16 (W-ext transposed).
// Wext[k][c]: c<130 -> P row c of w1; 136<=c<266 -> Q row (c-136); else 0.
// k<64: y coeff; k==64: x0 coeff; k>64: 0.
__global__ __launch_bounds__(256) void k_init(const float* __restrict__ w1,
                                              double* __restrict__ acc,
                                              double* __restrict__ lse,
                                              unsigned short* __restrict__ wt) {
  int gid = blockIdx.x * 256 + threadIdx.x;
  if (gid < NLSE) { lse[2 * gid] = -INFINITY; lse[2 * gid + 1] = 0.0; }
  if (gid < 8) acc[gid] = 0.0;
  for (int u = threadIdx.x; u < 16 * 104; u += 256) {
    int c = 16 * blockIdx.x + u / 104;
    int k = u % 104;
    float val = 0.f;
    if (c < 130) {
      if (k < 64) val = w1[c * 131 + 1 + k];
      else if (k == 64) val = w1[c * 131];
    } else if (c >= 136 && c < 266) {
      int r = c - 136;
      if (k < 64) val = w1[r * 131 + 66 + k];
      else if (k == 64) val = w1[r * 131 + 65];
    }
    wt[(size_t)c * 104 + k] = f2bf(val);
  }
}

// k_preA: thread-per-node. Computes y=sinh(t)/t * z (bf16 row [96]: y[64], x0, zeros),
// x0, and the 6 discriminator dot folds. No shuffles, 1 exp pair per node.
__global__ __launch_bounds__(256) void k_preA(
    const float* __restrict__ z, const float* __restrict__ lin_w,
    float* __restrict__ X0, unsigned short* __restrict__ YBF,
    float4* __restrict__ ZA4, float4* __restrict__ ZB4) {
  __shared__ float WL[384];  // [6][64]: rows 0-2 = lin_w[r][0:64], 3-5 = lin_w[r][64:128]
  for (int u = threadIdx.x; u < 384; u += 256) {
    int rr = u >> 6, d = u & 63;
    WL[u] = (rr < 3) ? lin_w[rr * 128 + d] : lin_w[(rr - 3) * 128 + 64 + d];
  }
  __syncthreads();
  int n = blockIdx.x * 256 + threadIdx.x;
  if (n >= NN) return;
  const float4* zr = (const float4*)(z + (size_t)n * 64);
  const float4* wl4 = (const float4*)WL;
  float4 zc[16];
  float zn2 = 0.f, d0 = 0.f, d1 = 0.f, d2 = 0.f, d3 = 0.f, d4 = 0.f, d5 = 0.f;
#pragma unroll
  for (int c = 0; c < 16; ++c) {
    float4 v = zr[c];
    zc[c] = v;
    zn2 += v.x * v.x + v.y * v.y + v.z * v.z + v.w * v.w;
    float4 w0 = wl4[c];
    float4 w1r = wl4[16 + c];
    float4 w2r = wl4[32 + c];
    float4 w3 = wl4[48 + c];
    float4 w4 = wl4[64 + c];
    float4 w5 = wl4[80 + c];
    d0 += v.x * w0.x + v.y * w0.y + v.z * w0.z + v.w * w0.w;
    d1 += v.x * w1r.x + v.y * w1r.y + v.z * w1r.z + v.w * w1r.w;
    d2 += v.x * w2r.x + v.y * w2r.y + v.z * w2r.z + v.w * w2r.w;
    d3 += v.x * w3.x + v.y * w3.y + v.z * w3.z + v.w * w3.w;
    d4 += v.x * w4.x + v.y * w4.y + v.z * w4.z + v.w * w4.w;
    d5 += v.x * w5.x + v.y * w5.y + v.z * w5.z + v.w * w5.w;
  }
  float zn = fmaxf(sqrtf(zn2), 1e-15f);
  float t = 1.7320508075688772f * zn;
  float e = __expf(t);
  float sh = 0.5f * (e - __frcp_rn(e));
  float fac = (t < 1e-4f) ? (1.f + t * t * 0.16666667f) : (sh / t);  // sinh(t)/t
  float yn2 = fac * fac * zn2;
  float x0 = sqrtf(0.33333333333333333f + yn2);
  X0[n] = x0;
  ZA4[n] = make_float4(d0, d1, d2, 0.f);
  ZB4[n] = make_float4(d3, d4, d5, 0.f);
  ushort4* yrow4 = (ushort4*)(YBF + (size_t)n * 96);
#pragma unroll
  for (int c = 0; c < 16; ++c) {
    float4 v = zc[c];
    ushort4 o;
    o.x = f2bf(fac * v.x); o.y = f2bf(fac * v.y);
    o.z = f2bf(fac * v.z); o.w = f2bf(fac * v.w);
    yrow4[c] = o;
  }
  ushort4 xx; xx.x = f2bf(x0); xx.y = 0; xx.z = 0; xx.w = 0;
  yrow4[16] = xx;
  ushort4 zzero; zzero.x = 0; zzero.y = 0; zzero.z = 0; zzero.w = 0;
#pragma unroll
  for (int c = 17; c < 24; ++c) yrow4[c] = zzero;
}

// k_pqgemm: PQ[node][272] bf16 = Yext[node][96] @ WextT via mfma_f32_16x16x32_bf16.
// Persistent blocks: stage Wt (57,344 B) to LDS once, grid-stride over 16-node tiles.
// A frag: lane holds Yext[nb + (l&15)][32*ks + (l>>4)*8 + i]; B frag from LDS Wt rows.
// C: col(out)=l&15, row(node)=(l>>4)*4+reg [m89 layout].
__global__ __launch_bounds__(256) void k_pqgemm(
    const unsigned short* __restrict__ ybf, const unsigned short* __restrict__ wt,
    unsigned short* __restrict__ pqb) {
  __shared__ __align__(16) short WT[28672];  // 57,344 B
  {
    float4* d = (float4*)WT;
    const float4* s = (const float4*)wt;
    for (int u = threadIdx.x; u < 3584; u += 256) d[u] = s[u];
  }
  __syncthreads();
  const int l = threadIdx.x & 63;
  const int w = threadIdx.x >> 6;
  const int col = l & 15, kq = l >> 4;
  for (int tile = blockIdx.x * 4 + w; tile < NN / 16; tile += gridDim.x * 4) {
    const int nb = tile * 16;
    const char* arow = (const char*)ybf + (size_t)(nb + col) * 192 + kq * 16;
    bh8 a0 = *(const bh8*)(arow);
    bh8 a1 = *(const bh8*)(arow + 64);
    bh8 a2 = *(const bh8*)(arow + 128);
#pragma unroll
    for (int nt = 0; nt < 17; ++nt) {
      const short* wrow = WT + (nt * 16 + col) * 104 + kq * 8;
      bh8 b0 = *(const bh8*)(wrow);
      bh8 b1 = *(const bh8*)(wrow + 32);
      bh8 b2 = *(const bh8*)(wrow + 64);
      f32x4 acc = {0.f, 0.f, 0.f, 0.f};
      acc = __builtin_amdgcn_mfma_f32_16x16x32_bf16(a0, b0, acc, 0, 0, 0);
      acc = __builtin_amdgcn_mfma_f32_16x16x32_bf16(a1, b1, acc, 0, 0, 0);
      acc = __builtin_amdgcn_mfma_f32_16x16x32_bf16(a2, b2, acc, 0, 0, 0);
      int out = nt * 16 + col;
#pragma unroll
      for (int v = 0; v < 4; ++v) {
        int node = nb + kq * 4 + v;
        pqb[(size_t)node * 272 + out] = f2bf(acc[v]);
      }
    }
  }
}

// nll over 1M edges, thread-per-edge, from the ZA/ZB fold tables.
__global__ __launch_bounds__(256) void k_nll(
    const int* __restrict__ p0, const int* __restrict__ p1,
    const int* __restrict__ n0, const int* __restrict__ n1,
    const int* __restrict__ o0, const int* __restrict__ o1,
    const float4* __restrict__ ZA4, const float4* __restrict__ ZB4,
    const float* __restrict__ lin_b, double* __restrict__ acc) {
  __shared__ double rbuf[8];
  const float c0 = lin_b[0], c1 = lin_b[1], c2 = lin_b[2];
  const float wp = 1.f / (3.f * EPOS), wn = 1.f / (3.f * ENEG), wo = 1.f / (3.f * ENON);
  double s = 0.0;
  for (int e = blockIdx.x * blockDim.x + threadIdx.x; e < E3; e += gridDim.x * blockDim.x) {
    int i, j, tgt;
    float wgt;
    if (e < EPOS) { i = p0[e]; j = p1[e]; tgt = 0; wgt = wp; }
    else if (e < EPOS + ENEG) { int t = e - EPOS; i = n0[t]; j = n1[t]; tgt = 1; wgt = wn; }
    else { int t = e - EPOS - ENEG; i = o0[t]; j = o1[t]; tgt = 2; wgt = wo; }
    float4 a = ZA4[i], b = ZB4[j];
    float l0 = a.x + b.x + c0, l1 = a.y + b.y + c1, l2 = a.z + b.z + c2;
    float mx = fmaxf(l0, fmaxf(l1, l2));
    float lse = mx + logf(expf(l0 - mx) + expf(l1 - mx) + expf(l2 - mx));
    float lt = (tgt == 0) ? l0 : ((tgt == 1) ? l1 : l2);
    s += (double)((lse - lt) * wgt);
  }
  breduce2(s, 0.0, acc + 0, acc + 5, rbuf);
}

__device__ __forceinline__ float hsq(float mdot) {
  float th = fmaxf(-3.f * mdot, 1.f + 1e-7f);
  float ach = logf(th + sqrtf(th * th - 1.f));
  return fminf(ach * ach * (1.f / 3.f), 50.f);
}

// l1/l2 hinge: 8 lanes per edge over bf16 Y rows (128 B each).
__global__ __launch_bounds__(256) void k_struct(
    const int* __restrict__ p0, const int* __restrict__ p1, const int* __restrict__ pk,
    const int* __restrict__ n0, const int* __restrict__ n1, const int* __restrict__ nk,
    const unsigned short* __restrict__ ybf, const float* __restrict__ X0,
    double* __restrict__ acc) {
  __shared__ double rbuf[8];
  const int st = threadIdx.x & 7;
  int g = (blockIdx.x * blockDim.x + threadIdx.x) >> 3;
  const int gs = (gridDim.x * blockDim.x) >> 3;
  double s1 = 0.0, s2 = 0.0;
  for (int e = g; e < EPOS + ENEG; e += gs) {
    bool pos = e < EPOS;
    int i, j, kk;
    if (pos) { i = p0[e]; j = p1[e]; kk = pk[e]; }
    else { int t = e - EPOS; i = n0[t]; j = n1[t]; kk = nk[t]; }
    bh8 yi = *(const bh8*)(ybf + (size_t)i * 96 + 8 * st);
    bh8 yj = *(const bh8*)(ybf + (size_t)j * 96 + 8 * st);
    bh8 yk = *(const bh8*)(ybf + (size_t)kk * 96 + 8 * st);
    float dij = 0.f, dik = 0.f;
#pragma unroll
    for (int q = 0; q < 8; ++q) {
      float fi = b2f((unsigned short)yi[q]);
      dij += fi * b2f((unsigned short)yj[q]);
      dik += fi * b2f((unsigned short)yk[q]);
    }
#pragma unroll
    for (int m = 4; m; m >>= 1) {
      dij += __shfl_xor(dij, m, 64);
      dik += __shfl_xor(dik, m, 64);
    }
    if (st == 0) {
      float x0i = X0[i], x0j = X0[j], x0k = X0[kk];
      float sij = hsq(dij - x0i * x0j);
      float sik = hsq(dik - x0i * x0k);
      if (pos) s1 += (double)fmaxf(sij - sik, 0.f);
      else s2 += (double)fmaxf(sik - sij, 0.f);
    }
  }
  breduce2(s1, s2, acc + 1, acc + 2, rbuf);
}

__device__ __forceinline__ void chunk_acc(bh8 p8, bh8 q8, const float* byp,
                                          const float* bys, const float* w2,
                                          float& sp, float& ss) {
#pragma unroll
  for (int q = 0; q < 8; ++q) {
    float a = b2f((unsigned short)p8[q]) + b2f((unsigned short)q8[q]);
    float w = w2[q];
    sp += fmaxf(a + byp[q], 0.f) * w;
    ss += fmaxf(a + bys[q], 0.f) * w;
  }
}

// l3: 16 lanes/edge; A = P[i] + Q[j] from bf16 PQ rows (272B per half).
// pred sum + stable streaming LSE for the shuffled exp branch.
__global__ __launch_bounds__(256) void k_info(
    const int* __restrict__ p0, const int* __restrict__ p1,
    const int* __restrict__ n0, const int* __restrict__ n1,
    const int* __restrict__ q0, const int* __restrict__ q1,
    const int* __restrict__ perm,
    const unsigned short* __restrict__ pqb,
    const float* __restrict__ w1, const float* __restrict__ b1v,
    const float* __restrict__ w2v, const float* __restrict__ b2v,
    double* __restrict__ acc, double* __restrict__ lse) {
  __shared__ float BYs[3][144];
  __shared__ float W2S[144];
  __shared__ float b2sh;
  __shared__ double rbuf[8];
  __shared__ double rbuf2[8];
  for (int k = threadIdx.x; k < 144; k += blockDim.x) {
    float bb = (k < 130) ? b1v[k] : 0.f;
    float wy = (k < 130) ? w1[k * 131 + 130] : 0.f;
    BYs[0][k] = bb;
    BYs[1][k] = bb + wy;
    BYs[2][k] = bb + 2.f * wy;
    W2S[k] = (k < 130) ? w2v[k] : 0.f;
  }
  if (threadIdx.x == 0) b2sh = b2v[0];
  __syncthreads();
  const double b2 = (double)b2sh;
  const float b2f_ = b2sh;
  const int s = threadIdx.x & 15;
  int g = (blockIdx.x * blockDim.x + threadIdx.x) >> 4;
  const int gs = (gridDim.x * blockDim.x) >> 4;
  double s1 = 0.0;
  double lm = -INFINITY, ls = 0.0;
  for (int e = g; e < E3; e += gs) {
    int i, j, ypi;
    if (e < EPOS) { i = p0[e]; j = p1[e]; ypi = 0; }
    else if (e < EPOS + ENEG) { int t = e - EPOS; i = n0[t]; j = n1[t]; ypi = 1; }
    else { int t = e - EPOS - ENEG; i = q0[t]; j = q1[t]; ypi = 2; }
    int p = perm[e];
    int ysi = (p < EPOS) ? 0 : ((p < EPOS + ENEG) ? 1 : 2);
    const unsigned short* pr = pqb + (size_t)i * 272;        // P half
    const unsigned short* qr = pqb + (size_t)j * 272 + 136;  // Q half
    float sp = 0.f, ss = 0.f;
    {
      bh8 p8 = *(const bh8*)(pr + 8 * s);
      bh8 q8 = *(const bh8*)(qr + 8 * s);
      int kb = 8 * s;
      chunk_acc(p8, q8, &BYs[ypi][kb], &BYs[ysi][kb], &W2S[kb], sp, ss);
    }
    if (s == 0) {  // chunk 16: k = 128..135 (130..135 have zero w2)
      bh8 p8 = *(const bh8*)(pr + 128);
      bh8 q8 = *(const bh8*)(qr + 128);
      chunk_acc(p8, q8, &BYs[ypi][128], &BYs[ysi][128], &W2S[128], sp, ss);
    }
#pragma unroll
    for (int m = 8; m; m >>= 1) {
      sp += __shfl_xor(sp, m, 64);
      ss += __shfl_xor(ss, m, 64);
    }
    if (s == 0) {
      s1 += (double)(sp + b2f_);
      double v = (double)ss + b2;
      if (v > lm) { ls = ls * exp(lm - v) + 1.0; lm = v; }
      else ls += exp(v - lm);
    }
  }
  breduce2(s1, 0.0, acc + 3, acc + 6, rbuf);
  lse_block_reduce(lm, ls, lse + 2 * blockIdx.x, rbuf2);
}

__global__ void k_final(const double* __restrict__ acc, const double* __restrict__ lse,
                        float* __restrict__ out) {
  __shared__ double rb[8];
  double lm = -INFINITY, ls = 0.0;
  for (int i = threadIdx.x; i < NLSE; i += blockDim.x)
    lse_combine(lm, ls, lse[2 * i], lse[2 * i + 1]);
#pragma unroll
  for (int d = 32; d; d >>= 1) {
    double om = __shfl_xor(lm, d, 64);
    double os = __shfl_xor(ls, d, 64);
    lse_combine(lm, ls, om, os);
  }
  int l = threadIdx.x & 63, w = threadIdx.x >> 6;
  if (l == 0) { rb[2 * w] = lm; rb[2 * w + 1] = ls; }
  __syncthreads();
  if (threadIdx.x == 0) {
    double M = rb[0], S = rb[1];
    int nw = blockDim.x >> 6;
    for (int i = 1; i < nw; ++i) lse_combine(M, S, rb[2 * i], rb[2 * i + 1]);
    double logmean = M + log(S) - log((double)E3);  // stable; ref overflows to +inf
    double nll = acc[0];
    double l1 = acc[1] / (double)EPOS;
    double l2 = acc[2] / (double)ENEG;
    double s1m = acc[3] / (double)E3;
    double l3 = -(s1m - logmean);
    out[0] = (float)(nll + 5.0 * (l1 + l2) + 0.1 * l3);
  }
}

extern "C" void kernel_launch(void* const* d_in, const int* in_sizes, int n_in,
                              void* d_out, int out_size, void* d_ws, size_t ws_size,
                              hipStream_t stream) {
  const float* z     = (const float*)d_in[0];
  const float* lin_w = (const float*)d_in[1];
  const float* lin_b = (const float*)d_in[2];
  const float* w1    = (const float*)d_in[3];
  const float* b1v   = (const float*)d_in[4];
  const float* w2v   = (const float*)d_in[5];
  const float* b2v   = (const float*)d_in[6];
  const int* pos  = (const int*)d_in[7];
  const int* neg  = (const int*)d_in[8];
  const int* non  = (const int*)d_in[9];
  const int* non2 = (const int*)d_in[10];
  const int* posk = (const int*)d_in[11];
  const int* negk = (const int*)d_in[12];
  const int* perm = (const int*)d_in[13];

  char* ws = (char*)d_ws;
  double* acc = (double*)(ws + ACC_OFF);
  double* lse = (double*)(ws + LSE_OFF);
  float* X0   = (float*)(ws + X0_OFF);
  unsigned short* YBF = (unsigned short*)(ws + YBF_OFF);
  float4* ZA4 = (float4*)(ws + ZA_OFF);
  float4* ZB4 = (float4*)(ws + ZB_OFF);
  unsigned short* WT  = (unsigned short*)(ws + WT_OFF);
  unsigned short* PQB = (unsigned short*)(ws + PQ_OFF);

  hipLaunchKernelGGL(k_init, dim3(17), dim3(256), 0, stream, w1, acc, lse, WT);
  hipLaunchKernelGGL(k_preA, dim3((NN + 255) / 256), dim3(256), 0, stream,
                     z, lin_w, X0, YBF, ZA4, ZB4);
  hipLaunchKernelGGL(k_pqgemm, dim3(512), dim3(256), 0, stream, YBF, WT, PQB);
  hipLaunchKernelGGL(k_nll, dim3(2048), dim3(256), 0, stream,
                     pos, pos + EPOS, neg, neg + ENEG, non, non + ENON, ZA4, ZB4, lin_b, acc);
  hipLaunchKernelGGL(k_struct, dim3(2048), dim3(256), 0, stream,
                     pos, pos + EPOS, posk, neg, neg + ENEG, negk, YBF, X0, acc);
  hipLaunchKernelGGL(k_info, dim3(4096), dim3(256), 0, stream,
                     pos, pos + EPOS, neg, neg + ENEG, non2, non2 + ENON, perm,
                     PQB, w1, b1v, w2v, b2v, acc, lse);
  hipLaunchKernelGGL(k_final, dim3(1), dim3(256), 0, stream, acc, lse, (float*)d_out);
}

// Round 4
// 442.363 us; speedup vs baseline: 2.0648x; 1.0295x over previous
//
#include <hip/hip_runtime.h>
#include <math.h>

// Problem constants
#define NN    100000
#define EPOS  250000
#define ENEG  250000
#define ENON  500000
#define E3   1000000
#define NLSE  4096

// Workspace layout (bytes, 256B-aligned sections)
#define ACC_OFF 0
#define LSE_OFF 256
#define X0_OFF  66048
#define YBF_OFF 466176
#define ZA_OFF  19666176
#define ZB_OFF  21266176
#define WT_OFF  22866176
#define PQ_OFF  22923776   // 100k * 272 bf16 rows (544 B) = 54.4 MB -> ~77.3 MB total

typedef __attribute__((ext_vector_type(8))) short bh8;
typedef __attribute__((ext_vector_type(4))) float f32x4;

// acc slots: 0=nll, 1=l1_sum, 2=l2_sum, 3=s1(pred sum), 5/6 dummies

__device__ __forceinline__ unsigned short f2bf(float f) {
  unsigned u = __float_as_uint(f);
  unsigned r = (u + 0x7FFFu + ((u >> 16) & 1u)) >> 16;
  return (unsigned short)r;
}
__device__ __forceinline__ float b2f(unsigned short s) {
  return __uint_as_float(((unsigned)s) << 16);
}
__device__ __forceinline__ float bflo(unsigned u) { return __uint_as_float(u << 16); }
__device__ __forceinline__ float bfhi(unsigned u) { return __uint_as_float(u & 0xFFFF0000u); }

__device__ __forceinline__ void breduce2(double v0, double v1, double* g0, double* g1,
                                         double* rbuf) {
#pragma unroll
  for (int m = 32; m; m >>= 1) {
    v0 += __shfl_xor(v0, m, 64);
    v1 += __shfl_xor(v1, m, 64);
  }
  int l = threadIdx.x & 63, w = threadIdx.x >> 6;
  if (l == 0) { rbuf[2 * w] = v0; rbuf[2 * w + 1] = v1; }
  __syncthreads();
  if (threadIdx.x == 0) {
    int nw = blockDim.x >> 6;
    double s0 = 0.0, s1 = 0.0;
    for (int i = 0; i < nw; ++i) { s0 += rbuf[2 * i]; s1 += rbuf[2 * i + 1]; }
    atomicAdd(g0, s0);
    atomicAdd(g1, s1);
  }
}

// Online log-sum-exp pair combine, guarded for -inf.
__device__ __forceinline__ void lse_combine(double& m, double& s, double om, double os) {
  double M = fmax(m, om);
  double sn = 0.0;
  if (m > -INFINITY) sn += s * exp(m - M);
  if (om > -INFINITY) sn += os * exp(om - M);
  m = M;
  s = sn;
}

__device__ __forceinline__ void lse_block_reduce(double lm, double ls, double* out_pair,
                                                 double* rbuf) {
#pragma unroll
  for (int d = 32; d; d >>= 1) {
    double om = __shfl_xor(lm, d, 64);
    double os = __shfl_xor(ls, d, 64);
    lse_combine(lm, ls, om, os);
  }
  __syncthreads();
  int l = threadIdx.x & 63, w = threadIdx.x >> 6;
  if (l == 0) { rbuf[2 * w] = lm; rbuf[2 * w + 1] = ls; }
  __syncthreads();
  if (threadIdx.x == 0) {
    int nw = blockDim.x >> 6;
    double M = rbuf[0], S = rbuf[1];
    for (int i = 1; i < nw; ++i) lse_combine(M, S, rbuf[2 * i], rbuf[2 * i + 1]);
    out_pair[0] = M;
    out_pair[1] = S;
  }
}

// k_init: zero acc + lse pairs; build Wt_g [272 cols][104 k] bf16 (W-ext transposed).
__global__ __launch_bounds__(256) void k_init(const float* __restrict__ w1,
                                              double* __restrict__ acc,
                                              double* __restrict__ lse,
                                              unsigned short* __restrict__ wt) {
  int gid = blockIdx.x * 256 + threadIdx.x;
  if (gid < NLSE) { lse[2 * gid] = -INFINITY; lse[2 * gid + 1] = 0.0; }
  if (gid < 8) acc[gid] = 0.0;
  for (int u = threadIdx.x; u < 16 * 104; u += 256) {
    int c = 16 * blockIdx.x + u / 104;
    int k = u % 104;
    float val = 0.f;
    if (c < 130) {
      if (k < 64) val = w1[c * 131 + 1 + k];
      else if (k == 64) val = w1[c * 131];
    } else if (c >= 136 && c < 266) {
      int r = c - 136;
      if (k < 64) val = w1[r * 131 + 66 + k];
      else if (k == 64) val = w1[r * 131 + 65];
    }
    wt[(size_t)c * 104 + k] = f2bf(val);
  }
}

// k_preA: thread-per-node precompute (y bf16 row, x0, discriminator folds).
__global__ __launch_bounds__(256) void k_preA(
    const float* __restrict__ z, const float* __restrict__ lin_w,
    float* __restrict__ X0, unsigned short* __restrict__ YBF,
    float4* __restrict__ ZA4, float4* __restrict__ ZB4) {
  __shared__ float WL[384];
  for (int u = threadIdx.x; u < 384; u += 256) {
    int rr = u >> 6, d = u & 63;
    WL[u] = (rr < 3) ? lin_w[rr * 128 + d] : lin_w[(rr - 3) * 128 + 64 + d];
  }
  __syncthreads();
  int n = blockIdx.x * 256 + threadIdx.x;
  if (n >= NN) return;
  const float4* zr = (const float4*)(z + (size_t)n * 64);
  const float4* wl4 = (const float4*)WL;
  float4 zc[16];
  float zn2 = 0.f, d0 = 0.f, d1 = 0.f, d2 = 0.f, d3 = 0.f, d4 = 0.f, d5 = 0.f;
#pragma unroll
  for (int c = 0; c < 16; ++c) {
    float4 v = zr[c];
    zc[c] = v;
    zn2 += v.x * v.x + v.y * v.y + v.z * v.z + v.w * v.w;
    float4 w0 = wl4[c];
    float4 w1r = wl4[16 + c];
    float4 w2r = wl4[32 + c];
    float4 w3 = wl4[48 + c];
    float4 w4 = wl4[64 + c];
    float4 w5 = wl4[80 + c];
    d0 += v.x * w0.x + v.y * w0.y + v.z * w0.z + v.w * w0.w;
    d1 += v.x * w1r.x + v.y * w1r.y + v.z * w1r.z + v.w * w1r.w;
    d2 += v.x * w2r.x + v.y * w2r.y + v.z * w2r.z + v.w * w2r.w;
    d3 += v.x * w3.x + v.y * w3.y + v.z * w3.z + v.w * w3.w;
    d4 += v.x * w4.x + v.y * w4.y + v.z * w4.z + v.w * w4.w;
    d5 += v.x * w5.x + v.y * w5.y + v.z * w5.z + v.w * w5.w;
  }
  float zn = fmaxf(sqrtf(zn2), 1e-15f);
  float t = 1.7320508075688772f * zn;
  float e = __expf(t);
  float sh = 0.5f * (e - __frcp_rn(e));
  float fac = (t < 1e-4f) ? (1.f + t * t * 0.16666667f) : (sh / t);
  float yn2 = fac * fac * zn2;
  float x0 = sqrtf(0.33333333333333333f + yn2);
  X0[n] = x0;
  ZA4[n] = make_float4(d0, d1, d2, 0.f);
  ZB4[n] = make_float4(d3, d4, d5, 0.f);
  ushort4* yrow4 = (ushort4*)(YBF + (size_t)n * 96);
#pragma unroll
  for (int c = 0; c < 16; ++c) {
    float4 v = zc[c];
    ushort4 o;
    o.x = f2bf(fac * v.x); o.y = f2bf(fac * v.y);
    o.z = f2bf(fac * v.z); o.w = f2bf(fac * v.w);
    yrow4[c] = o;
  }
  ushort4 xx; xx.x = f2bf(x0); xx.y = 0; xx.z = 0; xx.w = 0;
  yrow4[16] = xx;
  ushort4 zzero; zzero.x = 0; zzero.y = 0; zzero.z = 0; zzero.w = 0;
#pragma unroll
  for (int c = 17; c < 24; ++c) yrow4[c] = zzero;
}

// k_pqgemm: PQ = Yext @ WextT via mfma_f32_16x16x32_bf16.
// New row layout (272 elems): P k=0..129 at [0..129] (tail k=128,129 at 128,129),
// Q tails at [130,131], Q k=0..127 at [136..263]. Slots 132..135, 264..271 unused.
__global__ __launch_bounds__(256) void k_pqgemm(
    const unsigned short* __restrict__ ybf, const unsigned short* __restrict__ wt,
    unsigned short* __restrict__ pqb) {
  __shared__ __align__(16) short WT[28672];
  {
    float4* d = (float4*)WT;
    const float4* s = (const float4*)wt;
    for (int u = threadIdx.x; u < 3584; u += 256) d[u] = s[u];
  }
  __syncthreads();
  const int l = threadIdx.x & 63;
  const int w = threadIdx.x >> 6;
  const int col = l & 15, kq = l >> 4;
  for (int tile = blockIdx.x * 4 + w; tile < NN / 16; tile += gridDim.x * 4) {
    const int nb = tile * 16;
    const char* arow = (const char*)ybf + (size_t)(nb + col) * 192 + kq * 16;
    bh8 a0 = *(const bh8*)(arow);
    bh8 a1 = *(const bh8*)(arow + 64);
    bh8 a2 = *(const bh8*)(arow + 128);
#pragma unroll
    for (int nt = 0; nt < 17; ++nt) {
      const short* wrow = WT + (nt * 16 + col) * 104 + kq * 8;
      bh8 b0 = *(const bh8*)(wrow);
      bh8 b1 = *(const bh8*)(wrow + 32);
      bh8 b2 = *(const bh8*)(wrow + 64);
      f32x4 acc = {0.f, 0.f, 0.f, 0.f};
      acc = __builtin_amdgcn_mfma_f32_16x16x32_bf16(a0, b0, acc, 0, 0, 0);
      acc = __builtin_amdgcn_mfma_f32_16x16x32_bf16(a1, b1, acc, 0, 0, 0);
      acc = __builtin_amdgcn_mfma_f32_16x16x32_bf16(a2, b2, acc, 0, 0, 0);
      int out = nt * 16 + col;
      int pos = out;
      bool wr = true;
      if (out >= 130) {
        if (out < 136) wr = false;          // P pad columns
        else if (out < 264) pos = out;      // Q main k=0..127
        else if (out == 264) pos = 130;     // Q tail k=128
        else if (out == 265) pos = 131;     // Q tail k=129
        else wr = false;                    // Q pad columns
      }
      if (wr) {
#pragma unroll
        for (int v = 0; v < 4; ++v) {
          int node = nb + kq * 4 + v;
          pqb[(size_t)node * 272 + pos] = f2bf(acc[v]);
        }
      }
    }
  }
}

// nll over 1M edges, thread-per-edge, from the ZA/ZB fold tables.
__global__ __launch_bounds__(256) void k_nll(
    const int* __restrict__ p0, const int* __restrict__ p1,
    const int* __restrict__ n0, const int* __restrict__ n1,
    const int* __restrict__ o0, const int* __restrict__ o1,
    const float4* __restrict__ ZA4, const float4* __restrict__ ZB4,
    const float* __restrict__ lin_b, double* __restrict__ acc) {
  __shared__ double rbuf[8];
  const float c0 = lin_b[0], c1 = lin_b[1], c2 = lin_b[2];
  const float wp = 1.f / (3.f * EPOS), wn = 1.f / (3.f * ENEG), wo = 1.f / (3.f * ENON);
  double s = 0.0;
  for (int e = blockIdx.x * blockDim.x + threadIdx.x; e < E3; e += gridDim.x * blockDim.x) {
    int i, j, tgt;
    float wgt;
    if (e < EPOS) { i = p0[e]; j = p1[e]; tgt = 0; wgt = wp; }
    else if (e < EPOS + ENEG) { int t = e - EPOS; i = n0[t]; j = n1[t]; tgt = 1; wgt = wn; }
    else { int t = e - EPOS - ENEG; i = o0[t]; j = o1[t]; tgt = 2; wgt = wo; }
    float4 a = ZA4[i], b = ZB4[j];
    float l0 = a.x + b.x + c0, l1 = a.y + b.y + c1, l2 = a.z + b.z + c2;
    float mx = fmaxf(l0, fmaxf(l1, l2));
    float lse = mx + logf(expf(l0 - mx) + expf(l1 - mx) + expf(l2 - mx));
    float lt = (tgt == 0) ? l0 : ((tgt == 1) ? l1 : l2);
    s += (double)((lse - lt) * wgt);
  }
  breduce2(s, 0.0, acc + 0, acc + 5, rbuf);
}

__device__ __forceinline__ float hsq(float mdot) {
  float th = fmaxf(-3.f * mdot, 1.f + 1e-7f);
  float ach = logf(th + sqrtf(th * th - 1.f));
  return fminf(ach * ach * (1.f / 3.f), 50.f);
}

// l1/l2 hinge: 8 lanes/edge over bf16 Y rows, 2-deep prefetch pipeline.
__global__ __launch_bounds__(256) void k_struct(
    const int* __restrict__ p0, const int* __restrict__ p1, const int* __restrict__ pk,
    const int* __restrict__ n0, const int* __restrict__ n1, const int* __restrict__ nk,
    const unsigned short* __restrict__ ybf, const float* __restrict__ X0,
    double* __restrict__ acc) {
  __shared__ double rbuf[8];
  const int st = threadIdx.x & 7;
  int g = (blockIdx.x * blockDim.x + threadIdx.x) >> 3;
  const int gs = (gridDim.x * blockDim.x) >> 3;
  float s1f = 0.f, s2f = 0.f;

  bool pos_c = false;
  bh8 yi_c = {}, yj_c = {}, yk_c = {};
  float xi_c = 0.f, xj_c = 0.f, xk_c = 0.f;

#define ST_FETCH(E, POS, YI, YJ, YK, XI, XJ, XK)                       \
  {                                                                    \
    int i, j, kk;                                                      \
    POS = (E) < EPOS;                                                  \
    if (POS) { i = p0[E]; j = p1[E]; kk = pk[E]; }                     \
    else { int t = (E) - EPOS; i = n0[t]; j = n1[t]; kk = nk[t]; }     \
    YI = *(const bh8*)(ybf + (size_t)i * 96 + 8 * st);                 \
    YJ = *(const bh8*)(ybf + (size_t)j * 96 + 8 * st);                 \
    YK = *(const bh8*)(ybf + (size_t)kk * 96 + 8 * st);                \
    if (st == 0) { XI = X0[i]; XJ = X0[j]; XK = X0[kk]; }              \
  }

  int e = g;
  if (e < EPOS + ENEG) ST_FETCH(e, pos_c, yi_c, yj_c, yk_c, xi_c, xj_c, xk_c);
  while (e < EPOS + ENEG) {
    int e2 = e + gs;
    bool pos_n = false;
    bh8 yi_n = {}, yj_n = {}, yk_n = {};
    float xi_n = 0.f, xj_n = 0.f, xk_n = 0.f;
    if (e2 < EPOS + ENEG) ST_FETCH(e2, pos_n, yi_n, yj_n, yk_n, xi_n, xj_n, xk_n);
    float dij = 0.f, dik = 0.f;
#pragma unroll
    for (int q = 0; q < 8; ++q) {
      float fi = b2f((unsigned short)yi_c[q]);
      dij = fmaf(fi, b2f((unsigned short)yj_c[q]), dij);
      dik = fmaf(fi, b2f((unsigned short)yk_c[q]), dik);
    }
#pragma unroll
    for (int m = 4; m; m >>= 1) {
      dij += __shfl_xor(dij, m, 64);
      dik += __shfl_xor(dik, m, 64);
    }
    if (st == 0) {
      float sij = hsq(dij - xi_c * xj_c);
      float sik = hsq(dik - xi_c * xk_c);
      if (pos_c) s1f += fmaxf(sij - sik, 0.f);
      else s2f += fmaxf(sik - sij, 0.f);
    }
    e = e2;
    pos_c = pos_n; yi_c = yi_n; yj_c = yj_n; yk_c = yk_n;
    xi_c = xi_n; xj_c = xj_n; xk_c = xk_n;
  }
  breduce2((double)s1f, (double)s2f, acc + 1, acc + 2, rbuf);
}

// l3: 16 lanes/edge; A = P[i] + Q[j] from the bf16 PQ table.
// Register-resident b1/wy/w2, float streaming LSE, 2-deep prefetch pipeline.
// b2 cancels exactly in l3 so it is omitted everywhere.
__global__ __launch_bounds__(256) void k_info(
    const int* __restrict__ p0, const int* __restrict__ p1,
    const int* __restrict__ n0, const int* __restrict__ n1,
    const int* __restrict__ q0, const int* __restrict__ q1,
    const int* __restrict__ perm,
    const unsigned short* __restrict__ pqb,
    const float* __restrict__ w1, const float* __restrict__ b1v,
    const float* __restrict__ w2v,
    double* __restrict__ acc, double* __restrict__ lse) {
  __shared__ double rbuf[8];
  __shared__ double rbuf2[8];
  const int s = threadIdx.x & 15;
  float by0r[8], wyr[8], w2r[8];
#pragma unroll
  for (int q = 0; q < 8; ++q) {
    int k = 8 * s + q;
    by0r[q] = b1v[k];
    wyr[q] = w1[k * 131 + 130];
    w2r[q] = w2v[k];
  }
  const float by0t0 = b1v[128], by0t1 = b1v[129];
  const float wyt0 = w1[128 * 131 + 130], wyt1 = w1[129 * 131 + 130];
  const float w2t0 = w2v[128], w2t1 = w2v[129];
  int g = (blockIdx.x * blockDim.x + threadIdx.x) >> 4;
  const int gs = (gridDim.x * blockDim.x) >> 4;
  float s1f = 0.f;
  float lm = -INFINITY, lsum = 0.f;

  int ypi_c = 0, ysi_c = 0;
  bh8 p8_c = {}, q8_c = {};
  unsigned pt_c = 0, qt_c = 0;

#define INFO_FETCH(E, YPI, YSI, P8, Q8, PT, QT)                                          \
  {                                                                                      \
    int i, j;                                                                            \
    if ((E) < EPOS) { i = p0[E]; j = p1[E]; YPI = 0; }                                   \
    else if ((E) < EPOS + ENEG) { int t = (E) - EPOS; i = n0[t]; j = n1[t]; YPI = 1; }   \
    else { int t = (E) - EPOS - ENEG; i = q0[t]; j = q1[t]; YPI = 2; }                   \
    int p = perm[E];                                                                     \
    YSI = (p < EPOS) ? 0 : ((p < EPOS + ENEG) ? 1 : 2);                                  \
    const char* ri = (const char*)pqb + (size_t)i * 544;                                 \
    const char* rj = (const char*)pqb + (size_t)j * 544;                                 \
    P8 = *(const bh8*)(ri + 16 * s);                                                     \
    Q8 = *(const bh8*)(rj + 272 + 16 * s);                                               \
    if (s == 0) { PT = *(const unsigned*)(ri + 256); QT = *(const unsigned*)(rj + 260); } \
  }

  int e = g;
  if (e < E3) INFO_FETCH(e, ypi_c, ysi_c, p8_c, q8_c, pt_c, qt_c);
  while (e < E3) {
    int e2 = e + gs;
    int ypi_n = 0, ysi_n = 0;
    bh8 p8_n = {}, q8_n = {};
    unsigned pt_n = 0, qt_n = 0;
    if (e2 < E3) INFO_FETCH(e2, ypi_n, ysi_n, p8_n, q8_n, pt_n, qt_n);

    float ypf = (float)ypi_c, ysf = (float)ysi_c;
    float sp = 0.f, ss = 0.f;
#pragma unroll
    for (int q = 0; q < 8; ++q) {
      float t = b2f((unsigned short)p8_c[q]) + b2f((unsigned short)q8_c[q]) + by0r[q];
      sp = fmaf(fmaxf(fmaf(ypf, wyr[q], t), 0.f), w2r[q], sp);
      ss = fmaf(fmaxf(fmaf(ysf, wyr[q], t), 0.f), w2r[q], ss);
    }
    if (s == 0) {
      float t0 = bflo(pt_c) + bflo(qt_c) + by0t0;
      float t1 = bfhi(pt_c) + bfhi(qt_c) + by0t1;
      sp += fmaxf(fmaf(ypf, wyt0, t0), 0.f) * w2t0 + fmaxf(fmaf(ypf, wyt1, t1), 0.f) * w2t1;
      ss += fmaxf(fmaf(ysf, wyt0, t0), 0.f) * w2t0 + fmaxf(fmaf(ysf, wyt1, t1), 0.f) * w2t1;
    }
#pragma unroll
    for (int m = 8; m; m >>= 1) {
      sp += __shfl_xor(sp, m, 64);
      ss += __shfl_xor(ss, m, 64);
    }
    if (s == 0) {
      s1f += sp;
      float nm = fmaxf(lm, ss);
      lsum = lsum * __expf(lm - nm) + __expf(ss - nm);
      lm = nm;
    }
    e = e2;
    ypi_c = ypi_n; ysi_c = ysi_n; p8_c = p8_n; q8_c = q8_n; pt_c = pt_n; qt_c = qt_n;
  }
  breduce2((double)s1f, 0.0, acc + 3, acc + 6, rbuf);
  double lmd = (lsum > 0.f) ? (double)lm : -INFINITY;
  lse_block_reduce(lmd, (double)lsum, lse + 2 * blockIdx.x, rbuf2);
}

__global__ void k_final(const double* __restrict__ acc, const double* __restrict__ lse,
                        float* __restrict__ out) {
  __shared__ double rb[8];
  double lm = -INFINITY, ls = 0.0;
  for (int i = threadIdx.x; i < NLSE; i += blockDim.x)
    lse_combine(lm, ls, lse[2 * i], lse[2 * i + 1]);
#pragma unroll
  for (int d = 32; d; d >>= 1) {
    double om = __shfl_xor(lm, d, 64);
    double os = __shfl_xor(ls, d, 64);
    lse_combine(lm, ls, om, os);
  }
  int l = threadIdx.x & 63, w = threadIdx.x >> 6;
  if (l == 0) { rb[2 * w] = lm; rb[2 * w + 1] = ls; }
  __syncthreads();
  if (threadIdx.x == 0) {
    double M = rb[0], S = rb[1];
    int nw = blockDim.x >> 6;
    for (int i = 1; i < nw; ++i) lse_combine(M, S, rb[2 * i], rb[2 * i + 1]);
    // b2 cancels between mean(pred) and logmeanexp(shuffle); omitted in both.
    double logmean = M + log(S) - log((double)E3);
    double nll = acc[0];
    double l1 = acc[1] / (double)EPOS;
    double l2 = acc[2] / (double)ENEG;
    double s1m = acc[3] / (double)E3;
    double l3 = -(s1m - logmean);
    out[0] = (float)(nll + 5.0 * (l1 + l2) + 0.1 * l3);
  }
}

extern "C" void kernel_launch(void* const* d_in, const int* in_sizes, int n_in,
                              void* d_out, int out_size, void* d_ws, size_t ws_size,
                              hipStream_t stream) {
  const float* z     = (const float*)d_in[0];
  const float* lin_w = (const float*)d_in[1];
  const float* lin_b = (const float*)d_in[2];
  const float* w1    = (const float*)d_in[3];
  const float* b1v   = (const float*)d_in[4];
  const float* w2v   = (const float*)d_in[5];
  const int* pos  = (const int*)d_in[7];
  const int* neg  = (const int*)d_in[8];
  const int* non  = (const int*)d_in[9];
  const int* non2 = (const int*)d_in[10];
  const int* posk = (const int*)d_in[11];
  const int* negk = (const int*)d_in[12];
  const int* perm = (const int*)d_in[13];

  char* ws = (char*)d_ws;
  double* acc = (double*)(ws + ACC_OFF);
  double* lse = (double*)(ws + LSE_OFF);
  float* X0   = (float*)(ws + X0_OFF);
  unsigned short* YBF = (unsigned short*)(ws + YBF_OFF);
  float4* ZA4 = (float4*)(ws + ZA_OFF);
  float4* ZB4 = (float4*)(ws + ZB_OFF);
  unsigned short* WT  = (unsigned short*)(ws + WT_OFF);
  unsigned short* PQB = (unsigned short*)(ws + PQ_OFF);

  hipLaunchKernelGGL(k_init, dim3(17), dim3(256), 0, stream, w1, acc, lse, WT);
  hipLaunchKernelGGL(k_preA, dim3((NN + 255) / 256), dim3(256), 0, stream,
                     z, lin_w, X0, YBF, ZA4, ZB4);
  hipLaunchKernelGGL(k_pqgemm, dim3(512), dim3(256), 0, stream, YBF, WT, PQB);
  hipLaunchKernelGGL(k_nll, dim3(2048), dim3(256), 0, stream,
                     pos, pos + EPOS, neg, neg + ENEG, non, non + ENON, ZA4, ZB4, lin_b, acc);
  hipLaunchKernelGGL(k_struct, dim3(2048), dim3(256), 0, stream,
                     pos, pos + EPOS, posk, neg, neg + ENEG, negk, YBF, X0, acc);
  hipLaunchKernelGGL(k_info, dim3(4096), dim3(256), 0, stream,
                     pos, pos + EPOS, neg, neg + ENEG, non2, non2 + ENON, perm,
                     PQB, w1, b1v, w2v, acc, lse);
  hipLaunchKernelGGL(k_final, dim3(1), dim3(256), 0, stream, acc, lse, (float*)d_out);
}

// Round 5
// 279.475 us; speedup vs baseline: 3.2682x; 1.5828x over previous
//
#include <hip/hip_runtime.h>
#include <hip/hip_fp16.h>
#include <math.h>

// Problem constants
#define NN    100000
#define EPOS  250000
#define ENEG  250000
#define ENON  500000
#define E3   1000000
#define NLSE  4096

// k_edges phase split
#define NB_INFO   2560
#define NB_STRUCT 1024
#define NB_NLL    512
#define NB_EDGES  (NB_INFO + NB_STRUCT + NB_NLL)

// Workspace layout (bytes, 16B-aligned sections)
#define ACC_OFF 0
#define LSE_OFF 256
#define X0_OFF  66048
#define ZA_OFF  466176
#define ZB_OFF  2066176
#define WT_OFF  3666176      // 272x104 bf16 = 56,576
#define YBF_OFF 3722752      // 100k x 96 bf16 = 19,200,000
#define YF8_OFF 22922752     // 100k x 64 fp8  = 6,400,000
#define PT_OFF  29322752     // 100k x 2 fp8 tails (P k=128,129)
#define QT_OFF  29522752     // 100k x 2 fp8 tails (Q k=128,129)
#define PM_OFF  29722752     // 100k x 128 fp8 = 12,800,000
#define QM_OFF  42522752     // 100k x 128 fp8 = 12,800,000  -> total ~55.3 MB

typedef __attribute__((ext_vector_type(8))) short bh8;
typedef __attribute__((ext_vector_type(4))) float f32x4;
typedef __attribute__((ext_vector_type(2))) float f32x2;

// acc slots: 0=nll, 1=l1_sum, 2=l2_sum, 3=s1(pred sum), 5/6 dummies

__device__ __forceinline__ unsigned short f2bf(float f) {
  unsigned u = __float_as_uint(f);
  unsigned r = (u + 0x7FFFu + ((u >> 16) & 1u)) >> 16;
  return (unsigned short)r;
}

#if __has_builtin(__builtin_amdgcn_cvt_pk_f32_bf8) && __has_builtin(__builtin_amdgcn_cvt_pk_bf8_f32)
#define HAVE_BF8 1
#endif

// Decode 4 packed bf8 (e5m2) bytes -> 4 floats.
__device__ __forceinline__ void de4(unsigned v, float* o) {
#ifdef HAVE_BF8
  f32x2 lo = __builtin_amdgcn_cvt_pk_f32_bf8((int)v, false);
  f32x2 hi = __builtin_amdgcn_cvt_pk_f32_bf8((int)v, true);
  o[0] = lo[0]; o[1] = lo[1]; o[2] = hi[0]; o[3] = hi[1];
#else
  // e5m2 byte << 8 is a valid f16 (same exponent field)
  o[0] = __half2float(__ushort_as_half((unsigned short)((v & 0xFFu) << 8)));
  o[1] = __half2float(__ushort_as_half((unsigned short)(((v >> 8) & 0xFFu) << 8)));
  o[2] = __half2float(__ushort_as_half((unsigned short)(((v >> 16) & 0xFFu) << 8)));
  o[3] = __half2float(__ushort_as_half((unsigned short)((v >> 24) << 8)));
#endif
}

// Encode 2 floats -> 2 bf8 bytes (low 16 bits), clamped to finite e5m2 range.
__device__ __forceinline__ unsigned pk2(float a, float b) {
  a = fminf(fmaxf(a, -57344.f), 57344.f);
  b = fminf(fmaxf(b, -57344.f), 57344.f);
#ifdef HAVE_BF8
  return (unsigned)__builtin_amdgcn_cvt_pk_bf8_f32(a, b, 0, false) & 0xFFFFu;
#else
  unsigned short ha = __half_as_ushort(__float2half(a));
  unsigned short hb = __half_as_ushort(__float2half(b));
  ha = (unsigned short)((ha + 0x7Fu + ((ha >> 8) & 1u)) >> 8);
  hb = (unsigned short)((hb + 0x7Fu + ((hb >> 8) & 1u)) >> 8);
  return (unsigned)ha | ((unsigned)hb << 8);
#endif
}

__device__ __forceinline__ void breduce2(double v0, double v1, double* g0, double* g1,
                                         double* rbuf) {
#pragma unroll
  for (int m = 32; m; m >>= 1) {
    v0 += __shfl_xor(v0, m, 64);
    v1 += __shfl_xor(v1, m, 64);
  }
  int l = threadIdx.x & 63, w = threadIdx.x >> 6;
  if (l == 0) { rbuf[2 * w] = v0; rbuf[2 * w + 1] = v1; }
  __syncthreads();
  if (threadIdx.x == 0) {
    int nw = blockDim.x >> 6;
    double s0 = 0.0, s1 = 0.0;
    for (int i = 0; i < nw; ++i) { s0 += rbuf[2 * i]; s1 += rbuf[2 * i + 1]; }
    atomicAdd(g0, s0);
    atomicAdd(g1, s1);
  }
}

__device__ __forceinline__ void lse_combine(double& m, double& s, double om, double os) {
  double M = fmax(m, om);
  double sn = 0.0;
  if (m > -INFINITY) sn += s * exp(m - M);
  if (om > -INFINITY) sn += os * exp(om - M);
  m = M;
  s = sn;
}

__device__ __forceinline__ void lse_block_reduce(double lm, double ls, double* out_pair,
                                                 double* rbuf) {
#pragma unroll
  for (int d = 32; d; d >>= 1) {
    double om = __shfl_xor(lm, d, 64);
    double os = __shfl_xor(ls, d, 64);
    lse_combine(lm, ls, om, os);
  }
  __syncthreads();
  int l = threadIdx.x & 63, w = threadIdx.x >> 6;
  if (l == 0) { rbuf[2 * w] = lm; rbuf[2 * w + 1] = ls; }
  __syncthreads();
  if (threadIdx.x == 0) {
    int nw = blockDim.x >> 6;
    double M = rbuf[0], S = rbuf[1];
    for (int i = 1; i < nw; ++i) lse_combine(M, S, rbuf[2 * i], rbuf[2 * i + 1]);
    out_pair[0] = M;
    out_pair[1] = S;
  }
}

// k_init: zero acc + lse pairs; build Wt_g [272 cols][104 k] bf16 (W-ext transposed).
__global__ __launch_bounds__(256) void k_init(const float* __restrict__ w1,
                                              double* __restrict__ acc,
                                              double* __restrict__ lse,
                                              unsigned short* __restrict__ wt) {
  int gid = blockIdx.x * 256 + threadIdx.x;
  if (gid < NLSE) { lse[2 * gid] = -INFINITY; lse[2 * gid + 1] = 0.0; }
  if (gid < 8) acc[gid] = 0.0;
  for (int u = threadIdx.x; u < 16 * 104; u += 256) {
    int c = 16 * blockIdx.x + u / 104;
    int k = u % 104;
    float val = 0.f;
    if (c < 130) {
      if (k < 64) val = w1[c * 131 + 1 + k];
      else if (k == 64) val = w1[c * 131];
    } else if (c >= 136 && c < 266) {
      int r = c - 136;
      if (k < 64) val = w1[r * 131 + 66 + k];
      else if (k == 64) val = w1[r * 131 + 65];
    }
    wt[(size_t)c * 104 + k] = f2bf(val);
  }
}

// k_preA: thread-per-node precompute: y (bf16 row for GEMM, fp8 row for struct),
// x0, discriminator folds.
__global__ __launch_bounds__(256) void k_preA(
    const float* __restrict__ z, const float* __restrict__ lin_w,
    float* __restrict__ X0, unsigned short* __restrict__ YBF,
    unsigned char* __restrict__ YF8,
    float4* __restrict__ ZA4, float4* __restrict__ ZB4) {
  __shared__ float WL[384];
  for (int u = threadIdx.x; u < 384; u += 256) {
    int rr = u >> 6, d = u & 63;
    WL[u] = (rr < 3) ? lin_w[rr * 128 + d] : lin_w[(rr - 3) * 128 + 64 + d];
  }
  __syncthreads();
  int n = blockIdx.x * 256 + threadIdx.x;
  if (n >= NN) return;
  const float4* zr = (const float4*)(z + (size_t)n * 64);
  const float4* wl4 = (const float4*)WL;
  float4 zc[16];
  float zn2 = 0.f, d0 = 0.f, d1 = 0.f, d2 = 0.f, d3 = 0.f, d4 = 0.f, d5 = 0.f;
#pragma unroll
  for (int c = 0; c < 16; ++c) {
    float4 v = zr[c];
    zc[c] = v;
    zn2 += v.x * v.x + v.y * v.y + v.z * v.z + v.w * v.w;
    float4 w0 = wl4[c];
    float4 w1r = wl4[16 + c];
    float4 w2r = wl4[32 + c];
    float4 w3 = wl4[48 + c];
    float4 w4 = wl4[64 + c];
    float4 w5 = wl4[80 + c];
    d0 += v.x * w0.x + v.y * w0.y + v.z * w0.z + v.w * w0.w;
    d1 += v.x * w1r.x + v.y * w1r.y + v.z * w1r.z + v.w * w1r.w;
    d2 += v.x * w2r.x + v.y * w2r.y + v.z * w2r.z + v.w * w2r.w;
    d3 += v.x * w3.x + v.y * w3.y + v.z * w3.z + v.w * w3.w;
    d4 += v.x * w4.x + v.y * w4.y + v.z * w4.z + v.w * w4.w;
    d5 += v.x * w5.x + v.y * w5.y + v.z * w5.z + v.w * w5.w;
  }
  float zn = fmaxf(sqrtf(zn2), 1e-15f);
  float t = 1.7320508075688772f * zn;
  float e = __expf(t);
  float sh = 0.5f * (e - __frcp_rn(e));
  float fac = (t < 1e-4f) ? (1.f + t * t * 0.16666667f) : (sh / t);
  float yn2 = fac * fac * zn2;
  float x0 = sqrtf(0.33333333333333333f + yn2);
  X0[n] = x0;
  ZA4[n] = make_float4(d0, d1, d2, 0.f);
  ZB4[n] = make_float4(d3, d4, d5, 0.f);
  // bf16 row for the PQ GEMM
  ushort4* yrow4 = (ushort4*)(YBF + (size_t)n * 96);
#pragma unroll
  for (int c = 0; c < 16; ++c) {
    float4 v = zc[c];
    ushort4 o;
    o.x = f2bf(fac * v.x); o.y = f2bf(fac * v.y);
    o.z = f2bf(fac * v.z); o.w = f2bf(fac * v.w);
    yrow4[c] = o;
  }
  ushort4 xx; xx.x = f2bf(x0); xx.y = 0; xx.z = 0; xx.w = 0;
  yrow4[16] = xx;
  ushort4 zzero; zzero.x = 0; zzero.y = 0; zzero.z = 0; zzero.w = 0;
#pragma unroll
  for (int c = 17; c < 24; ++c) yrow4[c] = zzero;
  // fp8 row for k_struct
  unsigned yu[16];
#pragma unroll
  for (int c = 0; c < 16; ++c) {
    float4 v = zc[c];
    yu[c] = pk2(fac * v.x, fac * v.y) | (pk2(fac * v.z, fac * v.w) << 16);
  }
  uint4* y8 = (uint4*)(YF8 + (size_t)n * 64);
  y8[0] = make_uint4(yu[0], yu[1], yu[2], yu[3]);
  y8[1] = make_uint4(yu[4], yu[5], yu[6], yu[7]);
  y8[2] = make_uint4(yu[8], yu[9], yu[10], yu[11]);
  y8[3] = make_uint4(yu[12], yu[13], yu[14], yu[15]);
}

// k_pqgemm: PQ = Yext @ WextT via mfma_f32_16x16x32_bf16, fp8 e5m2 outputs.
// P main k=0..127 -> Pm[node][128] (one cache line), tails k=128,129 -> PT[node].
// Q main k=0..127 -> Qm[node][128], tails -> QT[node].
__global__ __launch_bounds__(256) void k_pqgemm(
    const unsigned short* __restrict__ ybf, const unsigned short* __restrict__ wt,
    unsigned char* __restrict__ Pm, unsigned char* __restrict__ Qm,
    unsigned char* __restrict__ PTb, unsigned char* __restrict__ QTb) {
  __shared__ __align__(16) short WTs[28288];
  {
    float4* d = (float4*)WTs;
    const float4* s = (const float4*)wt;
    for (int u = threadIdx.x; u < 3536; u += 256) d[u] = s[u];
  }
  __syncthreads();
  const int l = threadIdx.x & 63;
  const int w = threadIdx.x >> 6;
  const int col = l & 15, kq = l >> 4;
  for (int tile = blockIdx.x * 4 + w; tile < NN / 16; tile += gridDim.x * 4) {
    const int nb = tile * 16;
    const unsigned short* arow = ybf + (size_t)(nb + col) * 96 + kq * 8;
    bh8 a0 = *(const bh8*)(arow);
    bh8 a1 = *(const bh8*)(arow + 32);
    bh8 a2 = *(const bh8*)(arow + 64);
#pragma unroll
    for (int nt = 0; nt < 17; ++nt) {
      const short* wrow = WTs + (nt * 16 + col) * 104 + kq * 8;
      bh8 b0 = *(const bh8*)(wrow);
      bh8 b1 = *(const bh8*)(wrow + 32);
      bh8 b2 = *(const bh8*)(wrow + 64);
      f32x4 acc = {0.f, 0.f, 0.f, 0.f};
      acc = __builtin_amdgcn_mfma_f32_16x16x32_bf16(a0, b0, acc, 0, 0, 0);
      acc = __builtin_amdgcn_mfma_f32_16x16x32_bf16(a1, b1, acc, 0, 0, 0);
      acc = __builtin_amdgcn_mfma_f32_16x16x32_bf16(a2, b2, acc, 0, 0, 0);
      int out = nt * 16 + col;
      bool pmain = out < 128;
      bool ptail = (out == 128) | (out == 129);
      bool qmain = (out >= 136) & (out < 264);
      bool qtail = (out == 264) | (out == 265);
      if (pmain | ptail | qmain | qtail) {
        unsigned pk01 = pk2(acc[0], acc[1]);
        unsigned pk23 = pk2(acc[2], acc[3]);
        unsigned char by[4] = {(unsigned char)(pk01 & 255u), (unsigned char)((pk01 >> 8) & 255u),
                               (unsigned char)(pk23 & 255u), (unsigned char)((pk23 >> 8) & 255u)};
#pragma unroll
        for (int v = 0; v < 4; ++v) {
          size_t node = (size_t)(nb + kq * 4 + v);
          if (pmain) Pm[node * 128 + out] = by[v];
          else if (ptail) PTb[node * 2 + (out - 128)] = by[v];
          else if (qmain) Qm[node * 128 + (out - 136)] = by[v];
          else QTb[node * 2 + (out - 264)] = by[v];
        }
      }
    }
  }
}

__device__ __forceinline__ float hsq(float mdot) {
  float th = fmaxf(-3.f * mdot, 1.f + 1e-7f);
  float ach = __logf(th + sqrtf(th * th - 1.f));
  return fminf(ach * ach * (1.f / 3.f), 50.f);
}

// k_edges: fused nll + struct + info, phase by block range.
__global__ __launch_bounds__(256) void k_edges(
    const int* __restrict__ p0, const int* __restrict__ p1,
    const int* __restrict__ n0, const int* __restrict__ n1,
    const int* __restrict__ o0, const int* __restrict__ o1,   // none (nll)
    const int* __restrict__ q0, const int* __restrict__ q1,   // none2 (info)
    const int* __restrict__ pk, const int* __restrict__ nk,
    const int* __restrict__ perm,
    const unsigned char* __restrict__ Pm, const unsigned char* __restrict__ Qm,
    const unsigned short* __restrict__ PT, const unsigned short* __restrict__ QT,
    const unsigned char* __restrict__ YF8, const float* __restrict__ X0,
    const float4* __restrict__ ZA4, const float4* __restrict__ ZB4,
    const float* __restrict__ lin_b,
    const float* __restrict__ w1, const float* __restrict__ b1v,
    const float* __restrict__ w2v,
    double* __restrict__ acc, double* __restrict__ lse) {
  __shared__ double rbuf[8];
  __shared__ double rbuf2[8];

  if (blockIdx.x < NB_INFO) {
    // ---------------- info phase: 8 lanes/edge ----------------
    const int s8 = threadIdx.x & 7;
    float byr[16], wyr[16], w2r[16];
#pragma unroll
    for (int q = 0; q < 16; ++q) {
      int k = 16 * s8 + q;
      byr[q] = b1v[k];
      wyr[q] = w1[k * 131 + 130];
      w2r[q] = w2v[k];
    }
    const float byt0 = b1v[128], byt1 = b1v[129];
    const float wyt0 = w1[128 * 131 + 130], wyt1 = w1[129 * 131 + 130];
    const float w2t0 = w2v[128], w2t1 = w2v[129];
    int g = (blockIdx.x * 256 + threadIdx.x) >> 3;
    const int gs = (NB_INFO * 256) >> 3;
    float s1f = 0.f, lm = -INFINITY, lsum = 0.f;

    int ypi_c = 0, ysi_c = 0;
    uint4 P_c = {}, Q_c = {};
    unsigned pt_c = 0, qt_c = 0;

#define INFO_FETCH(E, YPI, YSI, P4, Q4, PT_, QT_)                                        \
  {                                                                                      \
    int i, j;                                                                            \
    if ((E) < EPOS) { i = p0[E]; j = p1[E]; YPI = 0; }                                   \
    else if ((E) < EPOS + ENEG) { int t = (E) - EPOS; i = n0[t]; j = n1[t]; YPI = 1; }   \
    else { int t = (E) - EPOS - ENEG; i = q0[t]; j = q1[t]; YPI = 2; }                   \
    int p = perm[E];                                                                     \
    YSI = (p < EPOS) ? 0 : ((p < EPOS + ENEG) ? 1 : 2);                                  \
    P4 = *(const uint4*)(Pm + (size_t)i * 128 + 16 * s8);                                \
    Q4 = *(const uint4*)(Qm + (size_t)j * 128 + 16 * s8);                                \
    if (s8 == 0) { PT_ = PT[i]; QT_ = QT[j]; }                                           \
  }

    int e = g;
    if (e < E3) INFO_FETCH(e, ypi_c, ysi_c, P_c, Q_c, pt_c, qt_c);
    while (e < E3) {
      int e2 = e + gs;
      int ypi_n = 0, ysi_n = 0;
      uint4 P_n = {}, Q_n = {};
      unsigned pt_n = 0, qt_n = 0;
      if (e2 < E3) INFO_FETCH(e2, ypi_n, ysi_n, P_n, Q_n, pt_n, qt_n);

      float pv[16], qv[16];
      de4(P_c.x, pv); de4(P_c.y, pv + 4); de4(P_c.z, pv + 8); de4(P_c.w, pv + 12);
      de4(Q_c.x, qv); de4(Q_c.y, qv + 4); de4(Q_c.z, qv + 8); de4(Q_c.w, qv + 12);
      float ypf = (float)ypi_c, ysf = (float)ysi_c;
      float sp = 0.f, ss = 0.f;
#pragma unroll
      for (int q = 0; q < 16; ++q) {
        float t = pv[q] + qv[q] + byr[q];
        sp = fmaf(fmaxf(fmaf(ypf, wyr[q], t), 0.f), w2r[q], sp);
        ss = fmaf(fmaxf(fmaf(ysf, wyr[q], t), 0.f), w2r[q], ss);
      }
      if (s8 == 0) {
        float tp[4], tq[4];
        de4(pt_c, tp); de4(qt_c, tq);
        float t0 = tp[0] + tq[0] + byt0;
        float t1 = tp[1] + tq[1] + byt1;
        sp += fmaxf(fmaf(ypf, wyt0, t0), 0.f) * w2t0 + fmaxf(fmaf(ypf, wyt1, t1), 0.f) * w2t1;
        ss += fmaxf(fmaf(ysf, wyt0, t0), 0.f) * w2t0 + fmaxf(fmaf(ysf, wyt1, t1), 0.f) * w2t1;
      }
#pragma unroll
      for (int m = 4; m; m >>= 1) {
        sp += __shfl_xor(sp, m, 64);
        ss += __shfl_xor(ss, m, 64);
      }
      if (s8 == 0) {
        s1f += sp;
        float nm = fmaxf(lm, ss);
        lsum = lsum * __expf(lm - nm) + __expf(ss - nm);
        lm = nm;
      }
      e = e2;
      ypi_c = ypi_n; ysi_c = ysi_n; P_c = P_n; Q_c = Q_n; pt_c = pt_n; qt_c = qt_n;
    }
    breduce2((double)s1f, 0.0, acc + 3, acc + 6, rbuf);
    double lmd = (lsum > 0.f) ? (double)lm : -(double)INFINITY;
    lse_block_reduce(lmd, (double)lsum, lse + 2 * blockIdx.x, rbuf2);

  } else if (blockIdx.x < NB_INFO + NB_STRUCT) {
    // ---------------- struct phase: 8 lanes/edge, fp8 Y ----------------
    const int st = threadIdx.x & 7;
    int g = ((blockIdx.x - NB_INFO) * 256 + threadIdx.x) >> 3;
    const int gs = (NB_STRUCT * 256) >> 3;
    float s1f = 0.f, s2f = 0.f;

    bool pos_c = false;
    uint2 yi_c = {}, yj_c = {}, yk_c = {};
    float xi_c = 0.f, xj_c = 0.f, xk_c = 0.f;

#define ST_FETCH(E, POS, YI, YJ, YK, XI, XJ, XK)                       \
  {                                                                    \
    int i, j, kk;                                                      \
    POS = (E) < EPOS;                                                  \
    if (POS) { i = p0[E]; j = p1[E]; kk = pk[E]; }                     \
    else { int t = (E) - EPOS; i = n0[t]; j = n1[t]; kk = nk[t]; }     \
    YI = *(const uint2*)(YF8 + (size_t)i * 64 + 8 * st);               \
    YJ = *(const uint2*)(YF8 + (size_t)j * 64 + 8 * st);               \
    YK = *(const uint2*)(YF8 + (size_t)kk * 64 + 8 * st);              \
    if (st == 0) { XI = X0[i]; XJ = X0[j]; XK = X0[kk]; }              \
  }

    int e = g;
    if (e < EPOS + ENEG) ST_FETCH(e, pos_c, yi_c, yj_c, yk_c, xi_c, xj_c, xk_c);
    while (e < EPOS + ENEG) {
      int e2 = e + gs;
      bool pos_n = false;
      uint2 yi_n = {}, yj_n = {}, yk_n = {};
      float xi_n = 0.f, xj_n = 0.f, xk_n = 0.f;
      if (e2 < EPOS + ENEG) ST_FETCH(e2, pos_n, yi_n, yj_n, yk_n, xi_n, xj_n, xk_n);
      float ai[8], aj[8], ak[8];
      de4(yi_c.x, ai); de4(yi_c.y, ai + 4);
      de4(yj_c.x, aj); de4(yj_c.y, aj + 4);
      de4(yk_c.x, ak); de4(yk_c.y, ak + 4);
      float dij = 0.f, dik = 0.f;
#pragma unroll
      for (int q = 0; q < 8; ++q) {
        dij = fmaf(ai[q], aj[q], dij);
        dik = fmaf(ai[q], ak[q], dik);
      }
#pragma unroll
      for (int m = 4; m; m >>= 1) {
        dij += __shfl_xor(dij, m, 64);
        dik += __shfl_xor(dik, m, 64);
      }
      if (st == 0) {
        float sij = hsq(dij - xi_c * xj_c);
        float sik = hsq(dik - xi_c * xk_c);
        if (pos_c) s1f += fmaxf(sij - sik, 0.f);
        else s2f += fmaxf(sik - sij, 0.f);
      }
      e = e2;
      pos_c = pos_n; yi_c = yi_n; yj_c = yj_n; yk_c = yk_n;
      xi_c = xi_n; xj_c = xj_n; xk_c = xk_n;
    }
    breduce2((double)s1f, (double)s2f, acc + 1, acc + 2, rbuf);

  } else {
    // ---------------- nll phase: thread-per-edge ----------------
    const float c0 = lin_b[0], c1 = lin_b[1], c2 = lin_b[2];
    const float wp = 1.f / (3.f * EPOS), wn = 1.f / (3.f * ENEG), wo = 1.f / (3.f * ENON);
    double s = 0.0;
    int t0 = (blockIdx.x - NB_INFO - NB_STRUCT) * 256 + threadIdx.x;
    for (int e = t0; e < E3; e += NB_NLL * 256) {
      int i, j, tgt;
      float wgt;
      if (e < EPOS) { i = p0[e]; j = p1[e]; tgt = 0; wgt = wp; }
      else if (e < EPOS + ENEG) { int t = e - EPOS; i = n0[t]; j = n1[t]; tgt = 1; wgt = wn; }
      else { int t = e - EPOS - ENEG; i = o0[t]; j = o1[t]; tgt = 2; wgt = wo; }
      float4 a = ZA4[i], b = ZB4[j];
      float l0 = a.x + b.x + c0, l1 = a.y + b.y + c1, l2 = a.z + b.z + c2;
      float mx = fmaxf(l0, fmaxf(l1, l2));
      float lsev = mx + __logf(__expf(l0 - mx) + __expf(l1 - mx) + __expf(l2 - mx));
      float lt = (tgt == 0) ? l0 : ((tgt == 1) ? l1 : l2);
      s += (double)((lsev - lt) * wgt);
    }
    breduce2(s, 0.0, acc + 0, acc + 5, rbuf);
  }
}

__global__ void k_final(const double* __restrict__ acc, const double* __restrict__ lse,
                        float* __restrict__ out) {
  __shared__ double rb[8];
  double lm = -INFINITY, ls = 0.0;
  for (int i = threadIdx.x; i < NLSE; i += blockDim.x)
    lse_combine(lm, ls, lse[2 * i], lse[2 * i + 1]);
#pragma unroll
  for (int d = 32; d; d >>= 1) {
    double om = __shfl_xor(lm, d, 64);
    double os = __shfl_xor(ls, d, 64);
    lse_combine(lm, ls, om, os);
  }
  int l = threadIdx.x & 63, w = threadIdx.x >> 6;
  if (l == 0) { rb[2 * w] = lm; rb[2 * w + 1] = ls; }
  __syncthreads();
  if (threadIdx.x == 0) {
    double M = rb[0], S = rb[1];
    int nw = blockDim.x >> 6;
    for (int i = 1; i < nw; ++i) lse_combine(M, S, rb[2 * i], rb[2 * i + 1]);
    // b2 cancels between mean(pred) and logmeanexp(shuffle); omitted in both.
    double logmean = M + log(S) - log((double)E3);
    double nll = acc[0];
    double l1 = acc[1] / (double)EPOS;
    double l2 = acc[2] / (double)ENEG;
    double s1m = acc[3] / (double)E3;
    double l3 = -(s1m - logmean);
    out[0] = (float)(nll + 5.0 * (l1 + l2) + 0.1 * l3);
  }
}

extern "C" void kernel_launch(void* const* d_in, const int* in_sizes, int n_in,
                              void* d_out, int out_size, void* d_ws, size_t ws_size,
                              hipStream_t stream) {
  const float* z     = (const float*)d_in[0];
  const float* lin_w = (const float*)d_in[1];
  const float* lin_b = (const float*)d_in[2];
  const float* w1    = (const float*)d_in[3];
  const float* b1v   = (const float*)d_in[4];
  const float* w2v   = (const float*)d_in[5];
  const int* pos  = (const int*)d_in[7];
  const int* neg  = (const int*)d_in[8];
  const int* non  = (const int*)d_in[9];
  const int* non2 = (const int*)d_in[10];
  const int* posk = (const int*)d_in[11];
  const int* negk = (const int*)d_in[12];
  const int* perm = (const int*)d_in[13];

  char* ws = (char*)d_ws;
  double* acc = (double*)(ws + ACC_OFF);
  double* lse = (double*)(ws + LSE_OFF);
  float* X0   = (float*)(ws + X0_OFF);
  float4* ZA4 = (float4*)(ws + ZA_OFF);
  float4* ZB4 = (float4*)(ws + ZB_OFF);
  unsigned short* WT  = (unsigned short*)(ws + WT_OFF);
  unsigned short* YBF = (unsigned short*)(ws + YBF_OFF);
  unsigned char* YF8  = (unsigned char*)(ws + YF8_OFF);
  unsigned char* PTb  = (unsigned char*)(ws + PT_OFF);
  unsigned char* QTb  = (unsigned char*)(ws + QT_OFF);
  unsigned char* PM   = (unsigned char*)(ws + PM_OFF);
  unsigned char* QM   = (unsigned char*)(ws + QM_OFF);

  hipLaunchKernelGGL(k_init, dim3(17), dim3(256), 0, stream, w1, acc, lse, WT);
  hipLaunchKernelGGL(k_preA, dim3((NN + 255) / 256), dim3(256), 0, stream,
                     z, lin_w, X0, YBF, YF8, ZA4, ZB4);
  hipLaunchKernelGGL(k_pqgemm, dim3(512), dim3(256), 0, stream, YBF, WT, PM, QM, PTb, QTb);
  hipLaunchKernelGGL(k_edges, dim3(NB_EDGES), dim3(256), 0, stream,
                     pos, pos + EPOS, neg, neg + ENEG, non, non + ENON,
                     non2, non2 + ENON, posk, negk, perm,
                     PM, QM, (const unsigned short*)PTb, (const unsigned short*)QTb,
                     YF8, X0, ZA4, ZB4, lin_b, w1, b1v, w2v, acc, lse);
  hipLaunchKernelGGL(k_final, dim3(1), dim3(256), 0, stream, acc, lse, (float*)d_out);
}